// Round 7
// baseline (298.844 us; speedup 1.0000x reference)
//
#include <hip/hip_runtime.h>

#define DD 128

constexpr int cN0 = 100000, cN1 = 50000, cN2 = 10000;

// ---------------------------------------------------------------------------
// bf16 helpers (packed 2x bf16 in a u32; lo 16 bits = even col, hi = odd col)
// ---------------------------------------------------------------------------
__device__ __forceinline__ float bf_lo(unsigned int u) {
  return __uint_as_float(u << 16);
}
__device__ __forceinline__ float bf_hi(unsigned int u) {
  return __uint_as_float(u & 0xFFFF0000u);
}
__device__ __forceinline__ unsigned int pack_bf2(float a, float b) {
  unsigned int ua = __float_as_uint(a), ub = __float_as_uint(b);
  ua += 0x7FFFu + ((ua >> 16) & 1u);   // round-to-nearest-even
  ub += 0x7FFFu + ((ub >> 16) & 1u);
  return (ua >> 16) | (ub & 0xFFFF0000u);
}

// ---------------------------------------------------------------------------
// fp32 -> packed bf16 conversion, 8 floats / thread.
// ---------------------------------------------------------------------------
__global__ __launch_bounds__(256) void cvt_bf16_kernel(
    const float* __restrict__ in, unsigned int* __restrict__ outp, long long n8) {
  long long i = (long long)blockIdx.x * 256 + threadIdx.x;
  if (i >= n8) return;
  const float4* f4 = reinterpret_cast<const float4*>(in) + i * 2;
  float4 a = f4[0];
  float4 b = f4[1];
  uint4 o;
  o.x = pack_bf2(a.x, a.y);
  o.y = pack_bf2(a.z, a.w);
  o.z = pack_bf2(b.x, b.y);
  o.w = pack_bf2(b.z, b.w);
  reinterpret_cast<uint4*>(outp)[i] = o;
}

// ---------------------------------------------------------------------------
// Transpose W (128x128): WT[d][c] = W[c][d].
// ---------------------------------------------------------------------------
__global__ __launch_bounds__(256) void wt_kernel(
    const float* __restrict__ W, float* __restrict__ WT) {
  int idx = blockIdx.x * 256 + threadIdx.x;
  int c = idx >> 7;
  int d = idx & 127;
  WT[d * DD + c] = W[idx];
}

// ---------------------------------------------------------------------------
// CSR step 1 (both graphs fused): contention-diluted histogram + rank.
// Counter cell = (dst, g) where g = e >> shift. Mean load/cell ~1 -> the
// atomicAdd-with-return chains that cost 86us in R6 disappear.
// ---------------------------------------------------------------------------
__global__ __launch_bounds__(256) void hist_rank2_kernel(
    const int* __restrict__ d1, int E1, int* __restrict__ cnt1,
    unsigned short* __restrict__ rank1, int sh1, int g1s,
    const int* __restrict__ d2, int E2, int* __restrict__ cnt2,
    unsigned short* __restrict__ rank2, int sh2, int g2s) {
  int e = blockIdx.x * 256 + threadIdx.x;
  if (e < E1) {
    int g = e >> sh1;
    rank1[e] = (unsigned short)atomicAdd(&cnt1[(size_t)d1[e] * g1s + g], 1);
  } else {
    e -= E1;
    if (e < E2) {
      int g = e >> sh2;
      rank2[e] = (unsigned short)atomicAdd(&cnt2[(size_t)d2[e] * g2s + g], 1);
    }
  }
}

// ---------------------------------------------------------------------------
// CSR step 2a: per-4096-chunk exclusive scan (256 thr x 16 elts via int4)
// -> ofs, chunk totals -> bsum. Blocks [0,nb1) graph 1, rest graph 2.
// n is always a multiple of 16, so each thread is fully in or out.
// ---------------------------------------------------------------------------
__global__ __launch_bounds__(256) void scan_blk2_kernel(
    const int* __restrict__ cnt1, int n1, int* __restrict__ ofs1, int* __restrict__ bsum1, int nb1,
    const int* __restrict__ cnt2, int n2, int* __restrict__ ofs2, int* __restrict__ bsum2) {
  const int* cnt; int n; int* ofs; int* bsum; int lb;
  if ((int)blockIdx.x < nb1) { cnt = cnt1; n = n1; ofs = ofs1; bsum = bsum1; lb = blockIdx.x; }
  else                       { cnt = cnt2; n = n2; ofs = ofs2; bsum = bsum2; lb = blockIdx.x - nb1; }

  __shared__ int tsum[256];
  int t = threadIdx.x;
  int base = lb * 4096 + t * 16;
  bool in = (base + 16 <= n);

  int v[16];
  if (in) {
    const int4* p4 = reinterpret_cast<const int4*>(cnt + base);
    int4 a = p4[0], b = p4[1], c = p4[2], d = p4[3];
    v[0]=a.x; v[1]=a.y; v[2]=a.z; v[3]=a.w;
    v[4]=b.x; v[5]=b.y; v[6]=b.z; v[7]=b.w;
    v[8]=c.x; v[9]=c.y; v[10]=c.z; v[11]=c.w;
    v[12]=d.x; v[13]=d.y; v[14]=d.z; v[15]=d.w;
  } else {
#pragma unroll
    for (int k = 0; k < 16; ++k) v[k] = 0;
  }
#pragma unroll
  for (int k = 1; k < 16; ++k) v[k] += v[k - 1];   // thread-local inclusive

  tsum[t] = v[15];
  __syncthreads();
  for (int d_ = 1; d_ < 256; d_ <<= 1) {
    int x = (t >= d_) ? tsum[t - d_] : 0;
    __syncthreads();
    tsum[t] += x;
    __syncthreads();
  }
  int ex = (t == 0) ? 0 : tsum[t - 1];

  if (in) {
    int4* q = reinterpret_cast<int4*>(ofs + base);
    q[0] = make_int4(ex,        ex + v[0],  ex + v[1],  ex + v[2]);
    q[1] = make_int4(ex + v[3], ex + v[4],  ex + v[5],  ex + v[6]);
    q[2] = make_int4(ex + v[7], ex + v[8],  ex + v[9],  ex + v[10]);
    q[3] = make_int4(ex + v[11], ex + v[12], ex + v[13], ex + v[14]);
  }
  if (t == 255) bsum[lb] = tsum[255];
}

// ---------------------------------------------------------------------------
// CSR step 2b: 1024-wide LDS scan of chunk sums (nb <= 1024). Block 0 ->
// graph 1, block 1 -> graph 2. Also writes the grand total to ofs[n].
// ---------------------------------------------------------------------------
__global__ __launch_bounds__(1024) void scan_bsum2_kernel(
    int* __restrict__ bsum1, int nb1, int* __restrict__ ofs1, int n1, int total1,
    int* __restrict__ bsum2, int nb2, int* __restrict__ ofs2, int n2, int total2) {
  int* bsum; int nb; int* ofs; int n; int total;
  if (blockIdx.x == 0) { bsum = bsum1; nb = nb1; ofs = ofs1; n = n1; total = total1; }
  else                 { bsum = bsum2; nb = nb2; ofs = ofs2; n = n2; total = total2; }

  __shared__ int part[1024];
  int t = threadIdx.x;
  int orig = (t < nb) ? bsum[t] : 0;
  part[t] = orig;
  __syncthreads();
  for (int d_ = 1; d_ < 1024; d_ <<= 1) {
    int x = (t >= d_) ? part[t - d_] : 0;
    __syncthreads();
    part[t] += x;
    __syncthreads();
  }
  if (t < nb) bsum[t] = part[t] - orig;   // exclusive
  if (t == 0) ofs[n] = total;
}

// ---------------------------------------------------------------------------
// CSR step 2c: add chunk base offsets (one bsum entry per 4096-chunk).
// ---------------------------------------------------------------------------
__global__ __launch_bounds__(256) void scan_add2_kernel(
    int* __restrict__ ofs1, int n1, const int* __restrict__ bsum1, int nb1,
    int* __restrict__ ofs2, int n2, const int* __restrict__ bsum2) {
  int* ofs; int n; const int* bsum; int lb;
  if ((int)blockIdx.x < nb1) { ofs = ofs1; n = n1; bsum = bsum1; lb = blockIdx.x; }
  else                       { ofs = ofs2; n = n2; bsum = bsum2; lb = blockIdx.x - nb1; }
  int add = bsum[lb];
  if (add == 0) return;  // uniform across block (lb==0 etc.)
  int base = lb * 4096 + threadIdx.x * 16;
  if (base + 16 <= n) {
    int4* q = reinterpret_cast<int4*>(ofs + base);
#pragma unroll
    for (int k = 0; k < 4; ++k) {
      int4 a = q[k];
      a.x += add; a.y += add; a.z += add; a.w += add;
      q[k] = a;
    }
  }
}

// ---------------------------------------------------------------------------
// CSR step 3 (both graphs fused): scatter (src, w) into dst-sorted order.
// pos = ofs[(d, g)] + rank. No atomics.
// ---------------------------------------------------------------------------
__global__ __launch_bounds__(256) void scatter2_kernel(
    const int* __restrict__ s1, const int* __restrict__ d1, const float* __restrict__ w1,
    const unsigned short* __restrict__ rank1, const int* __restrict__ ofs1,
    int E1, int sh1, int g1s, unsigned long long* __restrict__ sorted1,
    const int* __restrict__ s2, const int* __restrict__ d2, const float* __restrict__ w2,
    const unsigned short* __restrict__ rank2, const int* __restrict__ ofs2,
    int E2, int sh2, int g2s, unsigned long long* __restrict__ sorted2) {
  int e = blockIdx.x * 256 + threadIdx.x;
  if (e < E1) {
    int g = e >> sh1;
    int pos = ofs1[(size_t)d1[e] * g1s + g] + rank1[e];
    unsigned long long pk =
        (unsigned long long)(unsigned int)s1[e] |
        ((unsigned long long)__float_as_uint(w1[e]) << 32);
    __builtin_nontemporal_store(pk, sorted1 + pos);
  } else {
    e -= E1;
    if (e < E2) {
      int g = e >> sh2;
      int pos = ofs2[(size_t)d2[e] * g2s + g] + rank2[e];
      unsigned long long pk =
          (unsigned long long)(unsigned int)s2[e] |
          ((unsigned long long)__float_as_uint(w2[e]) << 32);
      __builtin_nontemporal_store(pk, sorted2 + pos);
    }
  }
}

// ===========================================================================
// bf16 gather SpMM. lane owns cols {2*lane, 2*lane+1} in one u32 (row=256B).
// ===========================================================================
#define GATHER_B(P, VX, VY)                                                \
  {                                                                        \
    int s_ = (int)(unsigned int)(P);                                       \
    unsigned int v_ = (h_in + (size_t)s_ * 64)[lane];                      \
    float w_ = __uint_as_float((unsigned int)((P) >> 32));                 \
    VX += bf_lo(v_) * w_;                                                  \
    VY += bf_hi(v_) * w_;                                                  \
  }

// SpMM block 1: xb (bf16) -> h1b (bf16). One wave per dst row.
// Node bucket = [ofs[row*g1s], ofs[(row+1)*g1s]).
__global__ __launch_bounds__(256) void spmm_csr_bf16_kernel(
    const unsigned int* __restrict__ h_in,
    const int* __restrict__ ofs, int g1s,
    const unsigned long long* __restrict__ sorted,
    unsigned int* __restrict__ h_out,
    int nrows) {
  int wave = (blockIdx.x * 256 + threadIdx.x) >> 6;
  int lane = threadIdx.x & 63;
  if (wave >= nrows) return;

  int lo = ofs[(size_t)wave * g1s];
  int hi = ofs[(size_t)(wave + 1) * g1s];

  float accx = 0.f, accy = 0.f;
  float ax1 = 0.f, ay1 = 0.f;
  int j = lo;
  for (; j + 8 <= hi; j += 8) {
    unsigned long long p0 = __builtin_nontemporal_load(sorted + j);
    unsigned long long p1 = __builtin_nontemporal_load(sorted + j + 1);
    unsigned long long p2 = __builtin_nontemporal_load(sorted + j + 2);
    unsigned long long p3 = __builtin_nontemporal_load(sorted + j + 3);
    unsigned long long p4 = __builtin_nontemporal_load(sorted + j + 4);
    unsigned long long p5 = __builtin_nontemporal_load(sorted + j + 5);
    unsigned long long p6 = __builtin_nontemporal_load(sorted + j + 6);
    unsigned long long p7 = __builtin_nontemporal_load(sorted + j + 7);
    GATHER_B(p0, accx, accy) GATHER_B(p1, ax1, ay1)
    GATHER_B(p2, accx, accy) GATHER_B(p3, ax1, ay1)
    GATHER_B(p4, accx, accy) GATHER_B(p5, ax1, ay1)
    GATHER_B(p6, accx, accy) GATHER_B(p7, ax1, ay1)
  }
  for (; j + 2 <= hi; j += 2) {
    unsigned long long p0 = __builtin_nontemporal_load(sorted + j);
    unsigned long long p1 = __builtin_nontemporal_load(sorted + j + 1);
    GATHER_B(p0, accx, accy) GATHER_B(p1, ax1, ay1)
  }
  if (j < hi) {
    unsigned long long p0 = __builtin_nontemporal_load(sorted + j);
    GATHER_B(p0, accx, accy)
  }

  (h_out + (size_t)wave * 64)[lane] = pack_bf2(accx + ax1, accy + ay1);
}

// SpMM block 2 (bf16 gather) + coalesced fp32 linear epilogue.
__global__ __launch_bounds__(256) void spmm_linear_bf16_kernel(
    const unsigned int* __restrict__ h_in,
    const int* __restrict__ ofs, int g2s,
    const unsigned long long* __restrict__ sorted,
    const float* __restrict__ WT,
    const float* __restrict__ b,
    float* __restrict__ out,
    int nrows) {
  __shared__ float hrow[4][DD];
  int wid  = threadIdx.x >> 6;
  int lane = threadIdx.x & 63;
  int row  = blockIdx.x * 4 + wid;
  if (row >= nrows) return;

  int lo = ofs[(size_t)row * g2s];
  int hi = ofs[(size_t)(row + 1) * g2s];

  float accx = 0.f, accy = 0.f;
  float ax1 = 0.f, ay1 = 0.f;
  int j = lo;
  for (; j + 4 <= hi; j += 4) {
    unsigned long long p0 = __builtin_nontemporal_load(sorted + j);
    unsigned long long p1 = __builtin_nontemporal_load(sorted + j + 1);
    unsigned long long p2 = __builtin_nontemporal_load(sorted + j + 2);
    unsigned long long p3 = __builtin_nontemporal_load(sorted + j + 3);
    GATHER_B(p0, accx, accy) GATHER_B(p1, ax1, ay1)
    GATHER_B(p2, accx, accy) GATHER_B(p3, ax1, ay1)
  }
  for (; j < hi; ++j) {
    unsigned long long p0 = __builtin_nontemporal_load(sorted + j);
    GATHER_B(p0, accx, accy)
  }

  hrow[wid][2 * lane]     = accx + ax1;
  hrow[wid][2 * lane + 1] = accy + ay1;
  // wave-synchronous: same wave writes then reads hrow[wid]

  const float2* bp = reinterpret_cast<const float2*>(b);
  float2 bb = bp[lane];
  float a0 = bb.x;
  float a1 = bb.y;
  const float* hr = hrow[wid];
#pragma unroll 8
  for (int d = 0; d < DD; ++d) {
    float h = hr[d];  // LDS broadcast
    float2 w = *reinterpret_cast<const float2*>(WT + (size_t)d * DD + 2 * lane);
    a0 += h * w.x;
    a1 += h * w.y;
  }
  float2 o;
  o.x = a0;
  o.y = a1;
  reinterpret_cast<float2*>(out + (size_t)row * DD)[lane] = o;
}
#undef GATHER_B

static inline size_t align256(size_t x) { return (x + 255) & ~size_t(255); }

extern "C" void kernel_launch(void* const* d_in, const int* in_sizes, int n_in,
                              void* d_out, int out_size, void* d_ws, size_t ws_size,
                              hipStream_t stream) {
  const float* x   = (const float*)d_in[0];
  const float* ew1 = (const float*)d_in[1];
  const float* ew2 = (const float*)d_in[2];
  const float* W   = (const float*)d_in[3];
  const float* b   = (const float*)d_in[4];
  const int* e1_src = (const int*)d_in[5];
  const int* e1_dst = (const int*)d_in[6];
  const int* e2_src = (const int*)d_in[7];
  const int* e2_dst = (const int*)d_in[8];
  float* out = (float*)d_out;

  int E1 = in_sizes[1];
  int E2 = in_sizes[2];

  // --- choose group-split (contention dilution) by workspace budget ---
  auto need = [&](int g1s, int g2s) -> size_t {
    size_t n1 = (size_t)cN1 * g1s, n2 = (size_t)cN2 * g2s;
    return align256((size_t)cN0 * DD * 2) +      // xb
           align256((size_t)cN1 * DD * 2) +      // h1b
           align256((size_t)DD * DD * 4) +       // WT
           align256((n1 + n2) * 4) +             // cnt
           align256((n1 + 1) * 4) +              // ofs1
           align256((n2 + 1) * 4) +              // ofs2
           2 * align256(4096) +                  // bsum
           align256((size_t)E1 * 2) + align256((size_t)E2 * 2) +  // rank u16
           align256((size_t)E1 * 8) + align256((size_t)E2 * 8);   // sorted
  };

  int sh1, g1s, sh2, g2s;
  if (ws_size >= need(32, 64))     { sh1 = 16; g1s = 32; sh2 = 13; g2s = 64; }
  else if (ws_size >= need(8, 8))  { sh1 = 18; g1s = 8;  sh2 = 16; g2s = 8;  }
  else                             { sh1 = 21; g1s = 1;  sh2 = 19; g2s = 1;  }

  size_t n1 = (size_t)cN1 * g1s, n2 = (size_t)cN2 * g2s;
  int nb1 = (int)((n1 + 4095) / 4096);
  int nb2 = (int)((n2 + 4095) / 4096);

  // ---- workspace layout ----
  char* p = (char*)d_ws;
  unsigned int* xb  = (unsigned int*)p;  p += align256((size_t)cN0 * DD * 2);
  unsigned int* h1b = (unsigned int*)p;  p += align256((size_t)cN1 * DD * 2);
  float* WT = (float*)p;                 p += align256((size_t)DD * DD * 4);
  int* cnt1 = (int*)p;
  int* cnt2 = cnt1 + n1;                 p += align256((n1 + n2) * 4);
  int* ofs1 = (int*)p;                   p += align256((n1 + 1) * 4);
  int* ofs2 = (int*)p;                   p += align256((n2 + 1) * 4);
  int* bsum1 = (int*)p;                  p += align256(4096);
  int* bsum2 = (int*)p;                  p += align256(4096);
  unsigned short* rank1 = (unsigned short*)p;  p += align256((size_t)E1 * 2);
  unsigned short* rank2 = (unsigned short*)p;  p += align256((size_t)E2 * 2);
  unsigned long long* sorted1 = (unsigned long long*)p;  p += align256((size_t)E1 * 8);
  unsigned long long* sorted2 = (unsigned long long*)p;  p += align256((size_t)E2 * 8);

  // 1) zero both count arrays in one memset
  hipMemsetAsync(cnt1, 0, (n1 + n2) * 4, stream);

  // 2) transpose W; convert x to bf16
  wt_kernel<<<64, 256, 0, stream>>>(W, WT);
  {
    long long n8 = (long long)cN0 * DD / 8;
    cvt_bf16_kernel<<<(int)((n8 + 255) / 256), 256, 0, stream>>>(x, xb, n8);
  }

  // 3) fused contention-diluted histogram + rank
  {
    int total = E1 + E2;
    hist_rank2_kernel<<<(total + 255) / 256, 256, 0, stream>>>(
        e1_dst, E1, cnt1, rank1, sh1, g1s,
        e2_dst, E2, cnt2, rank2, sh2, g2s);
  }

  // 4) 3-stage parallel scan over (n1, n2) counters
  scan_blk2_kernel<<<nb1 + nb2, 256, 0, stream>>>(
      cnt1, (int)n1, ofs1, bsum1, nb1, cnt2, (int)n2, ofs2, bsum2);
  scan_bsum2_kernel<<<2, 1024, 0, stream>>>(
      bsum1, nb1, ofs1, (int)n1, E1, bsum2, nb2, ofs2, (int)n2, E2);
  scan_add2_kernel<<<nb1 + nb2, 256, 0, stream>>>(
      ofs1, (int)n1, bsum1, nb1, ofs2, (int)n2, bsum2);

  // 5) fused scatter
  {
    int total = E1 + E2;
    scatter2_kernel<<<(total + 255) / 256, 256, 0, stream>>>(
        e1_src, e1_dst, ew1, rank1, ofs1, E1, sh1, g1s, sorted1,
        e2_src, e2_dst, ew2, rank2, ofs2, E2, sh2, g2s, sorted2);
  }

  int nrows = out_size / DD;  // N2

  // 6) SpMM block 1: xb -> h1b
  spmm_csr_bf16_kernel<<<(cN1 + 3) / 4, 256, 0, stream>>>(
      xb, ofs1, g1s, sorted1, h1b, cN1);

  // 7) SpMM block 2 + linear: h1b -> out
  spmm_linear_bf16_kernel<<<(nrows + 3) / 4, 256, 0, stream>>>(
      h1b, ofs2, g2s, sorted2, WT, b, out, nrows);
}

// Round 8
// 263.536 us; speedup vs baseline: 1.1340x; 1.1340x over previous
//
#include <hip/hip_runtime.h>

#define DD 128

constexpr int cN0 = 100000, cN1 = 50000, cN2 = 10000;
constexpr int NB1c = (cN1 + 31) / 32;   // 1563 coarse buckets (32 dsts each)
constexpr int NB2c = (cN2 + 31) / 32;   // 313

// ---------------------------------------------------------------------------
// bf16 helpers (packed 2x bf16 in a u32; lo 16 bits = even col, hi = odd col)
// ---------------------------------------------------------------------------
__device__ __forceinline__ float bf_lo(unsigned int u) {
  return __uint_as_float(u << 16);
}
__device__ __forceinline__ float bf_hi(unsigned int u) {
  return __uint_as_float(u & 0xFFFF0000u);
}
__device__ __forceinline__ unsigned int pack_bf2(float a, float b) {
  unsigned int ua = __float_as_uint(a), ub = __float_as_uint(b);
  ua += 0x7FFFu + ((ua >> 16) & 1u);   // round-to-nearest-even
  ub += 0x7FFFu + ((ub >> 16) & 1u);
  return (ua >> 16) | (ub & 0xFFFF0000u);
}

// ---------------------------------------------------------------------------
// fp32 -> packed bf16 conversion, 8 floats / thread.
// ---------------------------------------------------------------------------
__global__ __launch_bounds__(256) void cvt_bf16_kernel(
    const float* __restrict__ in, unsigned int* __restrict__ outp, long long n8) {
  long long i = (long long)blockIdx.x * 256 + threadIdx.x;
  if (i >= n8) return;
  const float4* f4 = reinterpret_cast<const float4*>(in) + i * 2;
  float4 a = f4[0];
  float4 b = f4[1];
  uint4 o;
  o.x = pack_bf2(a.x, a.y);
  o.y = pack_bf2(a.z, a.w);
  o.z = pack_bf2(b.x, b.y);
  o.w = pack_bf2(b.z, b.w);
  reinterpret_cast<uint4*>(outp)[i] = o;
}

// ---------------------------------------------------------------------------
// Transpose W (128x128): WT[d][c] = W[c][d].
// ---------------------------------------------------------------------------
__global__ __launch_bounds__(256) void wt_kernel(
    const float* __restrict__ W, float* __restrict__ WT) {
  int idx = blockIdx.x * 256 + threadIdx.x;
  int c = idx >> 7;
  int d = idx & 127;
  WT[d * DD + c] = W[idx];
}

// ---------------------------------------------------------------------------
// CSR pass A (both graphs fused): per-block (4096 edges) LDS histogram over
// coarse buckets (d>>5). Writes bucket-major (bucket, block) count matrix.
// NO global atomics.
// ---------------------------------------------------------------------------
__global__ __launch_bounds__(256) void passA_kernel(
    const int* __restrict__ d1, int E1, int nA1, int* __restrict__ bh1, int nblk1,
    const int* __restrict__ d2, int E2, int* __restrict__ bh2, int nblk2) {
  __shared__ int hist[NB1c];
  int lb = blockIdx.x;
  const int* dst; int E, NB, nblk; int* bh;
  if (lb < nA1) { dst = d1; E = E1; NB = NB1c; nblk = nblk1; bh = bh1; }
  else          { lb -= nA1; dst = d2; E = E2; NB = NB2c; nblk = nblk2; bh = bh2; }

  int t = threadIdx.x;
  for (int i = t; i < NB; i += 256) hist[i] = 0;
  __syncthreads();

  int eb = lb * 4096;
#pragma unroll
  for (int r = 0; r < 16; ++r) {
    int e = eb + r * 256 + t;
    if (e < E) atomicAdd(&hist[dst[e] >> 5], 1);
  }
  __syncthreads();
  for (int i = t; i < NB; i += 256) bh[(size_t)i * nblk + lb] = hist[i];
}

// ---------------------------------------------------------------------------
// Scan stage 1: per-4096-chunk exclusive scan (256 thr x 16 elts via int4)
// -> S, chunk totals -> bsum. Blocks [0,nb1) graph 1, rest graph 2.
// n must be a multiple of 16.
// ---------------------------------------------------------------------------
__global__ __launch_bounds__(256) void scan_blk2_kernel(
    const int* __restrict__ cnt1, int n1, int* __restrict__ ofs1, int* __restrict__ bsum1, int nb1,
    const int* __restrict__ cnt2, int n2, int* __restrict__ ofs2, int* __restrict__ bsum2) {
  const int* cnt; int n; int* ofs; int* bsum; int lb;
  if ((int)blockIdx.x < nb1) { cnt = cnt1; n = n1; ofs = ofs1; bsum = bsum1; lb = blockIdx.x; }
  else                       { cnt = cnt2; n = n2; ofs = ofs2; bsum = bsum2; lb = blockIdx.x - nb1; }

  __shared__ int tsum[256];
  int t = threadIdx.x;
  int base = lb * 4096 + t * 16;
  bool in = (base + 16 <= n);

  int v[16];
  if (in) {
    const int4* p4 = reinterpret_cast<const int4*>(cnt + base);
    int4 a = p4[0], b = p4[1], c = p4[2], d = p4[3];
    v[0]=a.x; v[1]=a.y; v[2]=a.z; v[3]=a.w;
    v[4]=b.x; v[5]=b.y; v[6]=b.z; v[7]=b.w;
    v[8]=c.x; v[9]=c.y; v[10]=c.z; v[11]=c.w;
    v[12]=d.x; v[13]=d.y; v[14]=d.z; v[15]=d.w;
  } else {
#pragma unroll
    for (int k = 0; k < 16; ++k) v[k] = 0;
  }
#pragma unroll
  for (int k = 1; k < 16; ++k) v[k] += v[k - 1];

  tsum[t] = v[15];
  __syncthreads();
  for (int d_ = 1; d_ < 256; d_ <<= 1) {
    int x = (t >= d_) ? tsum[t - d_] : 0;
    __syncthreads();
    tsum[t] += x;
    __syncthreads();
  }
  int ex = (t == 0) ? 0 : tsum[t - 1];

  if (in) {
    int4* q = reinterpret_cast<int4*>(ofs + base);
    q[0] = make_int4(ex,         ex + v[0],  ex + v[1],  ex + v[2]);
    q[1] = make_int4(ex + v[3],  ex + v[4],  ex + v[5],  ex + v[6]);
    q[2] = make_int4(ex + v[7],  ex + v[8],  ex + v[9],  ex + v[10]);
    q[3] = make_int4(ex + v[11], ex + v[12], ex + v[13], ex + v[14]);
  }
  if (t == 255) bsum[lb] = tsum[255];
}

// ---------------------------------------------------------------------------
// Scan stage 2: 1024-wide LDS scan of chunk sums (nb <= 1024).
// ---------------------------------------------------------------------------
__global__ __launch_bounds__(1024) void scan_bsum2_kernel(
    int* __restrict__ bsum1, int nb1, int* __restrict__ ofs1, int n1, int total1,
    int* __restrict__ bsum2, int nb2, int* __restrict__ ofs2, int n2, int total2) {
  int* bsum; int nb; int* ofs; int n; int total;
  if (blockIdx.x == 0) { bsum = bsum1; nb = nb1; ofs = ofs1; n = n1; total = total1; }
  else                 { bsum = bsum2; nb = nb2; ofs = ofs2; n = n2; total = total2; }

  __shared__ int part[1024];
  int t = threadIdx.x;
  int orig = (t < nb) ? bsum[t] : 0;
  part[t] = orig;
  __syncthreads();
  for (int d_ = 1; d_ < 1024; d_ <<= 1) {
    int x = (t >= d_) ? part[t - d_] : 0;
    __syncthreads();
    part[t] += x;
    __syncthreads();
  }
  if (t < nb) bsum[t] = part[t] - orig;   // exclusive
  if (t == 0) ofs[n] = total;
}

// ---------------------------------------------------------------------------
// Scan stage 3: add chunk base offsets.
// ---------------------------------------------------------------------------
__global__ __launch_bounds__(256) void scan_add2_kernel(
    int* __restrict__ ofs1, int n1, const int* __restrict__ bsum1, int nb1,
    int* __restrict__ ofs2, int n2, const int* __restrict__ bsum2) {
  int* ofs; int n; const int* bsum; int lb;
  if ((int)blockIdx.x < nb1) { ofs = ofs1; n = n1; bsum = bsum1; lb = blockIdx.x; }
  else                       { ofs = ofs2; n = n2; bsum = bsum2; lb = blockIdx.x - nb1; }
  int add = bsum[lb];
  if (add == 0) return;
  int base = lb * 4096 + threadIdx.x * 16;
  if (base + 16 <= n) {
    int4* q = reinterpret_cast<int4*>(ofs + base);
#pragma unroll
    for (int k = 0; k < 4; ++k) {
      int4 a = q[k];
      a.x += add; a.y += add; a.z += add; a.w += add;
      q[k] = a;
    }
  }
}

// ---------------------------------------------------------------------------
// CSR pass B (both graphs fused): scatter edge ids into coarse-bucket order.
// Rank within (block, bucket) assigned fresh via LDS returning atomics.
// coarse[pos] = (e << 5) | (d & 31).
// ---------------------------------------------------------------------------
__global__ __launch_bounds__(256) void passB_kernel(
    const int* __restrict__ d1, int E1, int nA1, const int* __restrict__ S1, int nblk1,
    unsigned int* __restrict__ coarse1,
    const int* __restrict__ d2, int E2, const int* __restrict__ S2, int nblk2,
    unsigned int* __restrict__ coarse2) {
  __shared__ int cnt[NB1c];
  int lb = blockIdx.x;
  const int* dst; int E, NB, nblk; const int* S; unsigned int* coarse;
  if (lb < nA1) { dst = d1; E = E1; NB = NB1c; nblk = nblk1; S = S1; coarse = coarse1; }
  else          { lb -= nA1; dst = d2; E = E2; NB = NB2c; nblk = nblk2; S = S2; coarse = coarse2; }

  int t = threadIdx.x;
  for (int i = t; i < NB; i += 256) cnt[i] = 0;
  __syncthreads();

  int eb = lb * 4096;
#pragma unroll
  for (int r = 0; r < 16; ++r) {
    int e = eb + r * 256 + t;
    if (e < E) {
      int d_ = dst[e];
      int b = d_ >> 5;
      int rk = atomicAdd(&cnt[b], 1);
      int pos = S[(size_t)b * nblk + lb] + rk;
      __builtin_nontemporal_store((unsigned int)((e << 5) | (d_ & 31)), coarse + pos);
    }
  }
}

// ---------------------------------------------------------------------------
// CSR fine pass: one block per coarse bucket. LDS 32-bin count/scan/rank ->
// final dst-sorted (src, w) array + per-dst CSR offsets. No global atomics.
// ---------------------------------------------------------------------------
__global__ __launch_bounds__(256) void fine_kernel(
    const int* __restrict__ s1, const float* __restrict__ w1, int E1,
    const int* __restrict__ S1, int nblk1, const unsigned int* __restrict__ coarse1,
    unsigned long long* __restrict__ sorted1, int* __restrict__ ofs1,
    const int* __restrict__ s2, const float* __restrict__ w2, int E2,
    const int* __restrict__ S2, int nblk2, const unsigned int* __restrict__ coarse2,
    unsigned long long* __restrict__ sorted2, int* __restrict__ ofs2) {
  __shared__ int h32[32], c32[32], binofs[32];
  int b = blockIdx.x;
  const int* src; const float* ew; int E, N, NB, nblk;
  const int* S; const unsigned int* coarse; unsigned long long* sorted; int* ofs;
  if (b < NB1c) {
    src = s1; ew = w1; E = E1; N = cN1; NB = NB1c; nblk = nblk1;
    S = S1; coarse = coarse1; sorted = sorted1; ofs = ofs1;
  } else {
    b -= NB1c;
    src = s2; ew = w2; E = E2; N = cN2; NB = NB2c; nblk = nblk2;
    S = S2; coarse = coarse2; sorted = sorted2; ofs = ofs2;
  }

  int t = threadIdx.x;
  int base = S[(size_t)b * nblk];
  int end  = (b + 1 < NB) ? S[(size_t)(b + 1) * nblk] : E;

  if (t < 32) { h32[t] = 0; c32[t] = 0; }
  __syncthreads();

  for (int i = base + t; i < end; i += 256)
    atomicAdd(&h32[coarse[i] & 31], 1);
  __syncthreads();

  if (t == 0) {
    int run = 0;
#pragma unroll
    for (int k = 0; k < 32; ++k) { binofs[k] = run; run += h32[k]; }
  }
  __syncthreads();

  int ndst = N - b * 32; if (ndst > 32) ndst = 32;
  if (t < ndst) ofs[b * 32 + t] = base + binofs[t];
  if (t == 0 && b == NB - 1) ofs[N] = E;

  for (int i = base + t; i < end; i += 256) {
    unsigned int c = coarse[i];
    int dl = c & 31;
    int e  = (int)(c >> 5);
    int r  = atomicAdd(&c32[dl], 1);
    int pos = base + binofs[dl] + r;
    unsigned long long pk =
        ((unsigned long long)__float_as_uint(ew[e]) << 32) | (unsigned int)src[e];
    __builtin_nontemporal_store(pk, sorted + pos);
  }
}

// ===========================================================================
// bf16 gather SpMM. lane owns cols {2*lane, 2*lane+1} in one u32 (row=256B).
// ===========================================================================
#define GATHER_B(P, VX, VY)                                                \
  {                                                                        \
    int s_ = (int)(unsigned int)(P);                                       \
    unsigned int v_ = (h_in + (size_t)s_ * 64)[lane];                      \
    float w_ = __uint_as_float((unsigned int)((P) >> 32));                 \
    VX += bf_lo(v_) * w_;                                                  \
    VY += bf_hi(v_) * w_;                                                  \
  }

// SpMM block 1: xb (bf16) -> h1b (bf16). One wave per dst row.
__global__ __launch_bounds__(256) void spmm_csr_bf16_kernel(
    const unsigned int* __restrict__ h_in,
    const int* __restrict__ ofs,
    const unsigned long long* __restrict__ sorted,
    unsigned int* __restrict__ h_out,
    int nrows) {
  int wave = (blockIdx.x * 256 + threadIdx.x) >> 6;
  int lane = threadIdx.x & 63;
  if (wave >= nrows) return;

  int lo = ofs[wave];
  int hi = ofs[wave + 1];

  float accx = 0.f, accy = 0.f;
  float ax1 = 0.f, ay1 = 0.f;
  int j = lo;
  for (; j + 8 <= hi; j += 8) {
    unsigned long long p0 = __builtin_nontemporal_load(sorted + j);
    unsigned long long p1 = __builtin_nontemporal_load(sorted + j + 1);
    unsigned long long p2 = __builtin_nontemporal_load(sorted + j + 2);
    unsigned long long p3 = __builtin_nontemporal_load(sorted + j + 3);
    unsigned long long p4 = __builtin_nontemporal_load(sorted + j + 4);
    unsigned long long p5 = __builtin_nontemporal_load(sorted + j + 5);
    unsigned long long p6 = __builtin_nontemporal_load(sorted + j + 6);
    unsigned long long p7 = __builtin_nontemporal_load(sorted + j + 7);
    GATHER_B(p0, accx, accy) GATHER_B(p1, ax1, ay1)
    GATHER_B(p2, accx, accy) GATHER_B(p3, ax1, ay1)
    GATHER_B(p4, accx, accy) GATHER_B(p5, ax1, ay1)
    GATHER_B(p6, accx, accy) GATHER_B(p7, ax1, ay1)
  }
  for (; j + 2 <= hi; j += 2) {
    unsigned long long p0 = __builtin_nontemporal_load(sorted + j);
    unsigned long long p1 = __builtin_nontemporal_load(sorted + j + 1);
    GATHER_B(p0, accx, accy) GATHER_B(p1, ax1, ay1)
  }
  if (j < hi) {
    unsigned long long p0 = __builtin_nontemporal_load(sorted + j);
    GATHER_B(p0, accx, accy)
  }

  (h_out + (size_t)wave * 64)[lane] = pack_bf2(accx + ax1, accy + ay1);
}

// SpMM block 2 (bf16 gather) + coalesced fp32 linear epilogue.
__global__ __launch_bounds__(256) void spmm_linear_bf16_kernel(
    const unsigned int* __restrict__ h_in,
    const int* __restrict__ ofs,
    const unsigned long long* __restrict__ sorted,
    const float* __restrict__ WT,
    const float* __restrict__ b,
    float* __restrict__ out,
    int nrows) {
  __shared__ float hrow[4][DD];
  int wid  = threadIdx.x >> 6;
  int lane = threadIdx.x & 63;
  int row  = blockIdx.x * 4 + wid;
  if (row >= nrows) return;

  int lo = ofs[row];
  int hi = ofs[row + 1];

  float accx = 0.f, accy = 0.f;
  float ax1 = 0.f, ay1 = 0.f;
  int j = lo;
  for (; j + 4 <= hi; j += 4) {
    unsigned long long p0 = __builtin_nontemporal_load(sorted + j);
    unsigned long long p1 = __builtin_nontemporal_load(sorted + j + 1);
    unsigned long long p2 = __builtin_nontemporal_load(sorted + j + 2);
    unsigned long long p3 = __builtin_nontemporal_load(sorted + j + 3);
    GATHER_B(p0, accx, accy) GATHER_B(p1, ax1, ay1)
    GATHER_B(p2, accx, accy) GATHER_B(p3, ax1, ay1)
  }
  for (; j < hi; ++j) {
    unsigned long long p0 = __builtin_nontemporal_load(sorted + j);
    GATHER_B(p0, accx, accy)
  }

  hrow[wid][2 * lane]     = accx + ax1;
  hrow[wid][2 * lane + 1] = accy + ay1;
  // wave-synchronous: same wave writes then reads hrow[wid]

  const float2* bp = reinterpret_cast<const float2*>(b);
  float2 bb = bp[lane];
  float a0 = bb.x;
  float a1 = bb.y;
  const float* hr = hrow[wid];
#pragma unroll 8
  for (int d = 0; d < DD; ++d) {
    float h = hr[d];  // LDS broadcast
    float2 w = *reinterpret_cast<const float2*>(WT + (size_t)d * DD + 2 * lane);
    a0 += h * w.x;
    a1 += h * w.y;
  }
  float2 o;
  o.x = a0;
  o.y = a1;
  reinterpret_cast<float2*>(out + (size_t)row * DD)[lane] = o;
}
#undef GATHER_B

static inline size_t align256(size_t x) { return (x + 255) & ~size_t(255); }
static inline int pad16(int x) { return (x + 15) & ~15; }

extern "C" void kernel_launch(void* const* d_in, const int* in_sizes, int n_in,
                              void* d_out, int out_size, void* d_ws, size_t ws_size,
                              hipStream_t stream) {
  const float* x   = (const float*)d_in[0];
  const float* ew1 = (const float*)d_in[1];
  const float* ew2 = (const float*)d_in[2];
  const float* W   = (const float*)d_in[3];
  const float* b   = (const float*)d_in[4];
  const int* e1_src = (const int*)d_in[5];
  const int* e1_dst = (const int*)d_in[6];
  const int* e2_src = (const int*)d_in[7];
  const int* e2_dst = (const int*)d_in[8];
  float* out = (float*)d_out;

  int E1 = in_sizes[1];
  int E2 = in_sizes[2];

  int nA1 = (E1 + 4095) / 4096;           // 391
  int nA2 = (E2 + 4095) / 4096;           // 79
  int nc1 = pad16(NB1c * nA1);            // cells, graph 1 (padded to x16)
  int nc2 = pad16(NB2c * nA2);
  int nbs1 = (nc1 + 4095) / 4096;         // scan chunks
  int nbs2 = (nc2 + 4095) / 4096;

  // ---- workspace layout (~67 MB) ----
  char* p = (char*)d_ws;
  unsigned int* xb  = (unsigned int*)p;  p += align256((size_t)cN0 * DD * 2);
  unsigned int* h1b = (unsigned int*)p;  p += align256((size_t)cN1 * DD * 2);
  float* WT = (float*)p;                 p += align256((size_t)DD * DD * 4);
  int* bh1 = (int*)p;                    p += align256((size_t)(nc1 + 16) * 4);
  int* bh2 = (int*)p;                    p += align256((size_t)(nc2 + 16) * 4);
  int* S1  = (int*)p;                    p += align256((size_t)(nc1 + 16) * 4);
  int* S2  = (int*)p;                    p += align256((size_t)(nc2 + 16) * 4);
  int* bsum1 = (int*)p;                  p += align256(4096);
  int* bsum2 = (int*)p;                  p += align256(4096);
  unsigned int* coarse1 = (unsigned int*)p;  p += align256((size_t)E1 * 4);
  unsigned int* coarse2 = (unsigned int*)p;  p += align256((size_t)E2 * 4);
  unsigned long long* sorted1 = (unsigned long long*)p;  p += align256((size_t)E1 * 8);
  unsigned long long* sorted2 = (unsigned long long*)p;  p += align256((size_t)E2 * 8);
  int* ofs1 = (int*)p;                   p += align256((size_t)(cN1 + 1) * 4);
  int* ofs2 = (int*)p;                   p += align256((size_t)(cN2 + 1) * 4);

  // 1) x -> bf16, W -> W^T (no memsets needed anywhere)
  {
    long long n8 = (long long)cN0 * DD / 8;
    cvt_bf16_kernel<<<(int)((n8 + 255) / 256), 256, 0, stream>>>(x, xb, n8);
  }
  wt_kernel<<<64, 256, 0, stream>>>(W, WT);

  // 2) pass A: per-block LDS coarse histograms -> (bucket, block) matrix
  passA_kernel<<<nA1 + nA2, 256, 0, stream>>>(
      e1_dst, E1, nA1, bh1, nA1, e2_dst, E2, bh2, nA2);

  // 3) scan the cell matrices (bucket-major) -> S
  scan_blk2_kernel<<<nbs1 + nbs2, 256, 0, stream>>>(
      bh1, nc1, S1, bsum1, nbs1, bh2, nc2, S2, bsum2);
  scan_bsum2_kernel<<<2, 1024, 0, stream>>>(
      bsum1, nbs1, S1, nc1, E1, bsum2, nbs2, S2, nc2, E2);
  scan_add2_kernel<<<nbs1 + nbs2, 256, 0, stream>>>(
      S1, nc1, bsum1, nbs1, S2, nc2, bsum2);

  // 4) pass B: scatter edge ids into coarse-bucket order (LDS ranks)
  passB_kernel<<<nA1 + nA2, 256, 0, stream>>>(
      e1_dst, E1, nA1, S1, nA1, coarse1,
      e2_dst, E2, S2, nA2, coarse2);

  // 5) fine pass: per-bucket 32-bin LDS sort -> sorted (src,w) + CSR ofs
  fine_kernel<<<NB1c + NB2c, 256, 0, stream>>>(
      e1_src, ew1, E1, S1, nA1, coarse1, sorted1, ofs1,
      e2_src, ew2, E2, S2, nA2, coarse2, sorted2, ofs2);

  int nrows = out_size / DD;  // N2

  // 6) SpMM block 1: xb -> h1b
  spmm_csr_bf16_kernel<<<(cN1 + 3) / 4, 256, 0, stream>>>(
      xb, ofs1, sorted1, h1b, cN1);

  // 7) SpMM block 2 + linear: h1b -> out
  spmm_linear_bf16_kernel<<<(nrows + 3) / 4, 256, 0, stream>>>(
      h1b, ofs2, sorted2, WT, b, out, nrows);
}

// Round 9
// 221.372 us; speedup vs baseline: 1.3500x; 1.1905x over previous
//
#include <hip/hip_runtime.h>

#define DD 128

constexpr int cN0 = 100000, cN1 = 50000, cN2 = 10000;
constexpr int NB1c = (cN1 + 31) / 32;   // 1563 coarse buckets (32 dsts each)
constexpr int NB2c = (cN2 + 31) / 32;   // 313
constexpr int CAP  = 4096;              // LDS payload capacity (4x mean: safe)

typedef unsigned long long ull;

// ---------------------------------------------------------------------------
// bf16 helpers (packed 2x bf16 in u32; lo 16 = even col, hi 16 = odd col)
// ---------------------------------------------------------------------------
__device__ __forceinline__ float bf_lo(unsigned int u) {
  return __uint_as_float(u << 16);
}
__device__ __forceinline__ float bf_hi(unsigned int u) {
  return __uint_as_float(u & 0xFFFF0000u);
}
__device__ __forceinline__ unsigned int pack_bf2(float a, float b) {
  unsigned int ua = __float_as_uint(a), ub = __float_as_uint(b);
  ua += 0x7FFFu + ((ua >> 16) & 1u);   // round-to-nearest-even
  ub += 0x7FFFu + ((ub >> 16) & 1u);
  return (ua >> 16) | (ub & 0xFFFF0000u);
}

// payload: hi32 = weight bits, lo32 = (src << 5) | dlow
#define PAY_GATHER(PK, VX, VY)                                       \
  {                                                                  \
    int s_ = ((int)(unsigned int)(PK)) >> 5;                         \
    unsigned int v_ = h_in[(size_t)s_ * 64 + lane];                  \
    float w_ = __uint_as_float((unsigned int)((PK) >> 32));          \
    VX += bf_lo(v_) * w_;                                            \
    VY += bf_hi(v_) * w_;                                            \
  }

// ---------------------------------------------------------------------------
// fp32 -> packed bf16, 8 floats / thread.
// ---------------------------------------------------------------------------
__global__ __launch_bounds__(256) void cvt_bf16_kernel(
    const float* __restrict__ in, unsigned int* __restrict__ outp, long long n8) {
  long long i = (long long)blockIdx.x * 256 + threadIdx.x;
  if (i >= n8) return;
  const float4* f4 = reinterpret_cast<const float4*>(in) + i * 2;
  float4 a = f4[0];
  float4 b = f4[1];
  uint4 o;
  o.x = pack_bf2(a.x, a.y);
  o.y = pack_bf2(a.z, a.w);
  o.z = pack_bf2(b.x, b.y);
  o.w = pack_bf2(b.z, b.w);
  reinterpret_cast<uint4*>(outp)[i] = o;
}

// ---------------------------------------------------------------------------
// Transpose W (128x128): WT[d][c] = W[c][d].
// ---------------------------------------------------------------------------
__global__ __launch_bounds__(256) void wt_kernel(
    const float* __restrict__ W, float* __restrict__ WT) {
  int idx = blockIdx.x * 256 + threadIdx.x;
  int c = idx >> 7;
  int d = idx & 127;
  WT[d * DD + c] = W[idx];
}

// ---------------------------------------------------------------------------
// Pass A (both graphs fused): per-block (4096 edges) LDS histogram over
// coarse buckets (d>>5) -> bucket-major (bucket, block) count matrix.
// ---------------------------------------------------------------------------
__global__ __launch_bounds__(256) void passA_kernel(
    const int* __restrict__ d1, int E1, int nA1, int* __restrict__ bh1, int nblk1,
    const int* __restrict__ d2, int E2, int* __restrict__ bh2, int nblk2) {
  __shared__ int hist[NB1c];
  int lb = blockIdx.x;
  const int* dst; int E, NB, nblk; int* bh;
  if (lb < nA1) { dst = d1; E = E1; NB = NB1c; nblk = nblk1; bh = bh1; }
  else          { lb -= nA1; dst = d2; E = E2; NB = NB2c; nblk = nblk2; bh = bh2; }

  int t = threadIdx.x;
  for (int i = t; i < NB; i += 256) hist[i] = 0;
  __syncthreads();

  int eb = lb * 4096;
#pragma unroll
  for (int r = 0; r < 16; ++r) {
    int e = eb + r * 256 + t;
    if (e < E) atomicAdd(&hist[dst[e] >> 5], 1);
  }
  __syncthreads();
  for (int i = t; i < NB; i += 256) bh[(size_t)i * nblk + lb] = hist[i];
}

// ---------------------------------------------------------------------------
// Scan stage 1: per-4096-chunk exclusive scan (256 thr x 16 via int4).
// ---------------------------------------------------------------------------
__global__ __launch_bounds__(256) void scan_blk2_kernel(
    const int* __restrict__ cnt1, int n1, int* __restrict__ ofs1, int* __restrict__ bsum1, int nb1,
    const int* __restrict__ cnt2, int n2, int* __restrict__ ofs2, int* __restrict__ bsum2) {
  const int* cnt; int n; int* ofs; int* bsum; int lb;
  if ((int)blockIdx.x < nb1) { cnt = cnt1; n = n1; ofs = ofs1; bsum = bsum1; lb = blockIdx.x; }
  else                       { cnt = cnt2; n = n2; ofs = ofs2; bsum = bsum2; lb = blockIdx.x - nb1; }

  __shared__ int tsum[256];
  int t = threadIdx.x;
  int base = lb * 4096 + t * 16;
  bool in = (base + 16 <= n);

  int v[16];
  if (in) {
    const int4* p4 = reinterpret_cast<const int4*>(cnt + base);
    int4 a = p4[0], b = p4[1], c = p4[2], d = p4[3];
    v[0]=a.x; v[1]=a.y; v[2]=a.z; v[3]=a.w;
    v[4]=b.x; v[5]=b.y; v[6]=b.z; v[7]=b.w;
    v[8]=c.x; v[9]=c.y; v[10]=c.z; v[11]=c.w;
    v[12]=d.x; v[13]=d.y; v[14]=d.z; v[15]=d.w;
  } else {
#pragma unroll
    for (int k = 0; k < 16; ++k) v[k] = 0;
  }
#pragma unroll
  for (int k = 1; k < 16; ++k) v[k] += v[k - 1];

  tsum[t] = v[15];
  __syncthreads();
  for (int d_ = 1; d_ < 256; d_ <<= 1) {
    int x = (t >= d_) ? tsum[t - d_] : 0;
    __syncthreads();
    tsum[t] += x;
    __syncthreads();
  }
  int ex = (t == 0) ? 0 : tsum[t - 1];

  if (in) {
    int4* q = reinterpret_cast<int4*>(ofs + base);
    q[0] = make_int4(ex,         ex + v[0],  ex + v[1],  ex + v[2]);
    q[1] = make_int4(ex + v[3],  ex + v[4],  ex + v[5],  ex + v[6]);
    q[2] = make_int4(ex + v[7],  ex + v[8],  ex + v[9],  ex + v[10]);
    q[3] = make_int4(ex + v[11], ex + v[12], ex + v[13], ex + v[14]);
  }
  if (t == 255) bsum[lb] = tsum[255];
}

// ---------------------------------------------------------------------------
// Scan stage 2: 1024-wide LDS scan of chunk sums (nb <= 1024).
// ---------------------------------------------------------------------------
__global__ __launch_bounds__(1024) void scan_bsum2_kernel(
    int* __restrict__ bsum1, int nb1, int* __restrict__ ofs1, int n1, int total1,
    int* __restrict__ bsum2, int nb2, int* __restrict__ ofs2, int n2, int total2) {
  int* bsum; int nb; int* ofs; int n; int total;
  if (blockIdx.x == 0) { bsum = bsum1; nb = nb1; ofs = ofs1; n = n1; total = total1; }
  else                 { bsum = bsum2; nb = nb2; ofs = ofs2; n = n2; total = total2; }

  __shared__ int part[1024];
  int t = threadIdx.x;
  int orig = (t < nb) ? bsum[t] : 0;
  part[t] = orig;
  __syncthreads();
  for (int d_ = 1; d_ < 1024; d_ <<= 1) {
    int x = (t >= d_) ? part[t - d_] : 0;
    __syncthreads();
    part[t] += x;
    __syncthreads();
  }
  if (t < nb) bsum[t] = part[t] - orig;   // exclusive
  if (t == 0) ofs[n] = total;
}

// ---------------------------------------------------------------------------
// Scan stage 3: add chunk base offsets.
// ---------------------------------------------------------------------------
__global__ __launch_bounds__(256) void scan_add2_kernel(
    int* __restrict__ ofs1, int n1, const int* __restrict__ bsum1, int nb1,
    int* __restrict__ ofs2, int n2, const int* __restrict__ bsum2) {
  int* ofs; int n; const int* bsum; int lb;
  if ((int)blockIdx.x < nb1) { ofs = ofs1; n = n1; bsum = bsum1; lb = blockIdx.x; }
  else                       { ofs = ofs2; n = n2; bsum = bsum2; lb = blockIdx.x - nb1; }
  int add = bsum[lb];
  if (add == 0) return;
  int base = lb * 4096 + threadIdx.x * 16;
  if (base + 16 <= n) {
    int4* q = reinterpret_cast<int4*>(ofs + base);
#pragma unroll
    for (int k = 0; k < 4; ++k) {
      int4 a = q[k];
      a.x += add; a.y += add; a.z += add; a.w += add;
      q[k] = a;
    }
  }
}

// ---------------------------------------------------------------------------
// Pass B (both graphs fused): scatter full 8B payload (w | src<<5 | dlow)
// into coarse-bucket order. Ranks via per-block LDS atomics. No global atomics.
// ---------------------------------------------------------------------------
__global__ __launch_bounds__(256) void passB_kernel(
    const int* __restrict__ d1, const int* __restrict__ s1, const float* __restrict__ w1,
    int E1, int nA1, const int* __restrict__ S1, int nblk1, ull* __restrict__ coarse1,
    const int* __restrict__ d2, const int* __restrict__ s2, const float* __restrict__ w2,
    int E2, const int* __restrict__ S2, int nblk2, ull* __restrict__ coarse2) {
  __shared__ int cnt[NB1c];
  int lb = blockIdx.x;
  const int* dst; const int* src; const float* ew;
  int E, NB, nblk; const int* S; ull* coarse;
  if (lb < nA1) {
    dst = d1; src = s1; ew = w1; E = E1; NB = NB1c; nblk = nblk1; S = S1; coarse = coarse1;
  } else {
    lb -= nA1;
    dst = d2; src = s2; ew = w2; E = E2; NB = NB2c; nblk = nblk2; S = S2; coarse = coarse2;
  }

  int t = threadIdx.x;
  for (int i = t; i < NB; i += 256) cnt[i] = 0;
  __syncthreads();

  int eb = lb * 4096;
#pragma unroll
  for (int r = 0; r < 16; ++r) {
    int e = eb + r * 256 + t;
    if (e < E) {
      int d_ = dst[e];
      int bkt = d_ >> 5;
      int rk = atomicAdd(&cnt[bkt], 1);
      int pos = S[(size_t)bkt * nblk + lb] + rk;
      ull pk = ((ull)__float_as_uint(ew[e]) << 32) |
               (unsigned int)((src[e] << 5) | (d_ & 31));
      __builtin_nontemporal_store(pk, coarse + pos);
    }
  }
}

// ---------------------------------------------------------------------------
// Fused fine-bin + SpMM block 1: one block per coarse bucket (32 dst rows).
// LDS 32-bin place of the bucket's payloads, then 4 waves x 8 rows gather
// from xb and write bf16 h1b rows. No global sorted array.
// ---------------------------------------------------------------------------
__global__ __launch_bounds__(256) void bucket_spmm1_kernel(
    const unsigned int* __restrict__ h_in,   // xb
    const int* __restrict__ S, int nblk,
    const ull* __restrict__ coarse,
    unsigned int* __restrict__ h1b) {
  __shared__ ull pay[CAP];
  __shared__ int h32[32], c32[32], binofs[32];
  int b = blockIdx.x;
  int t = threadIdx.x;
  int wid = t >> 6, lane = t & 63;

  int base = S[(size_t)b * nblk];
  int end  = S[(size_t)(b + 1) * nblk];
  int count = end - base;

  if (count <= CAP) {
    if (t < 32) { h32[t] = 0; c32[t] = 0; }
    __syncthreads();
    for (int i = base + t; i < end; i += 256)
      atomicAdd(&h32[(int)(unsigned int)coarse[i] & 31], 1);
    __syncthreads();
    if (t == 0) {
      int run = 0;
#pragma unroll
      for (int k = 0; k < 32; ++k) { binofs[k] = run; run += h32[k]; }
    }
    __syncthreads();
    for (int i = base + t; i < end; i += 256) {
      ull pk = coarse[i];
      int dl = (int)(unsigned int)pk & 31;
      int rk = atomicAdd(&c32[dl], 1);
      pay[binofs[dl] + rk] = pk;
    }
    __syncthreads();

#pragma unroll
    for (int r = 0; r < 8; ++r) {
      int dl = wid * 8 + r;
      int row = b * 32 + dl;
      if (row >= cN1) break;
      int lo = binofs[dl], hi = binofs[dl] + h32[dl];
      float accx = 0.f, accy = 0.f, ax1 = 0.f, ay1 = 0.f;
      int j = lo;
      for (; j + 4 <= hi; j += 4) {
        ull p0 = pay[j], p1 = pay[j + 1], p2 = pay[j + 2], p3 = pay[j + 3];
        PAY_GATHER(p0, accx, accy) PAY_GATHER(p1, ax1, ay1)
        PAY_GATHER(p2, accx, accy) PAY_GATHER(p3, ax1, ay1)
      }
      for (; j < hi; ++j) { ull p0 = pay[j]; PAY_GATHER(p0, accx, accy) }
      h1b[(size_t)row * 64 + lane] = pack_bf2(accx + ax1, accy + ay1);
    }
  } else {
    // slow fallback (statistically unreachable; kept for correctness)
    for (int r = 0; r < 8; ++r) {
      int dl = wid * 8 + r;
      int row = b * 32 + dl;
      if (row >= cN1) break;
      float accx = 0.f, accy = 0.f;
      for (int i = base; i < end; ++i) {
        ull pk = coarse[i];
        if (((int)(unsigned int)pk & 31) == dl) { PAY_GATHER(pk, accx, accy) }
      }
      h1b[(size_t)row * 64 + lane] = pack_bf2(accx, accy);
    }
  }
}

// ---------------------------------------------------------------------------
// Fused fine-bin + SpMM block 2 + linear: one block per coarse bucket of
// graph 2. Gather h2 rows into LDS (fp32), then each wave computes its 8
// rows' linear outputs simultaneously, streaming WT once per wave.
// ---------------------------------------------------------------------------
__global__ __launch_bounds__(256) void bucket_spmm2_linear_kernel(
    const unsigned int* __restrict__ h_in,   // h1b
    const int* __restrict__ S, int nblk,
    const ull* __restrict__ coarse,
    const float* __restrict__ WT,
    const float* __restrict__ bias,
    float* __restrict__ out) {
  __shared__ ull pay[CAP];
  __shared__ float hrow[32][DD];
  __shared__ int h32[32], c32[32], binofs[32];
  int b = blockIdx.x;
  int t = threadIdx.x;
  int wid = t >> 6, lane = t & 63;

  int base = S[(size_t)b * nblk];
  int end  = S[(size_t)(b + 1) * nblk];
  int count = end - base;

  if (count <= CAP) {
    if (t < 32) { h32[t] = 0; c32[t] = 0; }
    __syncthreads();
    for (int i = base + t; i < end; i += 256)
      atomicAdd(&h32[(int)(unsigned int)coarse[i] & 31], 1);
    __syncthreads();
    if (t == 0) {
      int run = 0;
#pragma unroll
      for (int k = 0; k < 32; ++k) { binofs[k] = run; run += h32[k]; }
    }
    __syncthreads();
    for (int i = base + t; i < end; i += 256) {
      ull pk = coarse[i];
      int dl = (int)(unsigned int)pk & 31;
      int rk = atomicAdd(&c32[dl], 1);
      pay[binofs[dl] + rk] = pk;
    }
    __syncthreads();

#pragma unroll
    for (int r = 0; r < 8; ++r) {
      int dl = wid * 8 + r;
      int row = b * 32 + dl;
      if (row >= cN2) break;
      int lo = binofs[dl], hi = binofs[dl] + h32[dl];
      float accx = 0.f, accy = 0.f, ax1 = 0.f, ay1 = 0.f;
      int j = lo;
      for (; j + 4 <= hi; j += 4) {
        ull p0 = pay[j], p1 = pay[j + 1], p2 = pay[j + 2], p3 = pay[j + 3];
        PAY_GATHER(p0, accx, accy) PAY_GATHER(p1, ax1, ay1)
        PAY_GATHER(p2, accx, accy) PAY_GATHER(p3, ax1, ay1)
      }
      for (; j < hi; ++j) { ull p0 = pay[j]; PAY_GATHER(p0, accx, accy) }
      float2 hv; hv.x = accx + ax1; hv.y = accy + ay1;
      *reinterpret_cast<float2*>(&hrow[dl][2 * lane]) = hv;
    }
  } else {
    for (int r = 0; r < 8; ++r) {
      int dl = wid * 8 + r;
      int row = b * 32 + dl;
      if (row >= cN2) break;
      float accx = 0.f, accy = 0.f;
      for (int i = base; i < end; ++i) {
        ull pk = coarse[i];
        if (((int)(unsigned int)pk & 31) == dl) { PAY_GATHER(pk, accx, accy) }
      }
      float2 hv; hv.x = accx; hv.y = accy;
      *reinterpret_cast<float2*>(&hrow[dl][2 * lane]) = hv;
    }
  }
  // wave-synchronous: each wave reads only the hrow rows it wrote.

  float2 bb = reinterpret_cast<const float2*>(bias)[lane];
  float a0[8], a1[8];
#pragma unroll
  for (int r = 0; r < 8; ++r) { a0[r] = bb.x; a1[r] = bb.y; }

  const float* hbase = &hrow[wid * 8][0];
#pragma unroll 4
  for (int d = 0; d < DD; ++d) {
    float2 wv = *reinterpret_cast<const float2*>(WT + (size_t)d * DD + 2 * lane);
#pragma unroll
    for (int r = 0; r < 8; ++r) {
      float h = hbase[r * DD + d];   // LDS broadcast
      a0[r] += h * wv.x;
      a1[r] += h * wv.y;
    }
  }
#pragma unroll
  for (int r = 0; r < 8; ++r) {
    int row = b * 32 + wid * 8 + r;
    if (row < cN2) {
      float2 o; o.x = a0[r]; o.y = a1[r];
      reinterpret_cast<float2*>(out + (size_t)row * DD)[lane] = o;
    }
  }
}

static inline size_t align256(size_t x) { return (x + 255) & ~size_t(255); }
static inline int pad16(int x) { return (x + 15) & ~15; }

extern "C" void kernel_launch(void* const* d_in, const int* in_sizes, int n_in,
                              void* d_out, int out_size, void* d_ws, size_t ws_size,
                              hipStream_t stream) {
  const float* x   = (const float*)d_in[0];
  const float* ew1 = (const float*)d_in[1];
  const float* ew2 = (const float*)d_in[2];
  const float* W   = (const float*)d_in[3];
  const float* b   = (const float*)d_in[4];
  const int* e1_src = (const int*)d_in[5];
  const int* e1_dst = (const int*)d_in[6];
  const int* e2_src = (const int*)d_in[7];
  const int* e2_dst = (const int*)d_in[8];
  float* out = (float*)d_out;

  int E1 = in_sizes[1];
  int E2 = in_sizes[2];

  int nA1 = (E1 + 4095) / 4096;           // 391
  int nA2 = (E2 + 4095) / 4096;           // 79
  int nc1 = pad16(NB1c * nA1);
  int nc2 = pad16(NB2c * nA2);
  int nbs1 = (nc1 + 4095) / 4096;         // 150
  int nbs2 = (nc2 + 4095) / 4096;         // 7

  // ---- workspace layout (~59 MB) ----
  char* p = (char*)d_ws;
  unsigned int* xb  = (unsigned int*)p;  p += align256((size_t)cN0 * DD * 2);
  unsigned int* h1b = (unsigned int*)p;  p += align256((size_t)cN1 * DD * 2);
  float* WT = (float*)p;                 p += align256((size_t)DD * DD * 4);
  int* bh1 = (int*)p;                    p += align256((size_t)(nc1 + 16) * 4);
  int* bh2 = (int*)p;                    p += align256((size_t)(nc2 + 16) * 4);
  int* S1  = (int*)p;                    p += align256((size_t)(nc1 + 16) * 4);
  int* S2  = (int*)p;                    p += align256((size_t)(nc2 + 16) * 4);
  int* bsum1 = (int*)p;                  p += align256(4096);
  int* bsum2 = (int*)p;                  p += align256(4096);
  ull* coarse1 = (ull*)p;                p += align256((size_t)E1 * 8);
  ull* coarse2 = (ull*)p;                p += align256((size_t)E2 * 8);

  // 1) x -> bf16; W -> W^T  (no memsets anywhere)
  {
    long long n8 = (long long)cN0 * DD / 8;
    cvt_bf16_kernel<<<(int)((n8 + 255) / 256), 256, 0, stream>>>(x, xb, n8);
  }
  wt_kernel<<<64, 256, 0, stream>>>(W, WT);

  // 2) pass A: coarse (bucket, block) histogram matrix
  passA_kernel<<<nA1 + nA2, 256, 0, stream>>>(
      e1_dst, E1, nA1, bh1, nA1, e2_dst, E2, bh2, nA2);

  // 3) scan -> S
  scan_blk2_kernel<<<nbs1 + nbs2, 256, 0, stream>>>(
      bh1, nc1, S1, bsum1, nbs1, bh2, nc2, S2, bsum2);
  scan_bsum2_kernel<<<2, 1024, 0, stream>>>(
      bsum1, nbs1, S1, nc1, E1, bsum2, nbs2, S2, nc2, E2);
  scan_add2_kernel<<<nbs1 + nbs2, 256, 0, stream>>>(
      S1, nc1, bsum1, nbs1, S2, nc2, bsum2);

  // 4) pass B: scatter full payloads into coarse-bucket order
  passB_kernel<<<nA1 + nA2, 256, 0, stream>>>(
      e1_dst, e1_src, ew1, E1, nA1, S1, nA1, coarse1,
      e2_dst, e2_src, ew2, E2, S2, nA2, coarse2);

  // 5) fused bin + SpMM block 1: xb -> h1b
  bucket_spmm1_kernel<<<NB1c, 256, 0, stream>>>(xb, S1, nA1, coarse1, h1b);

  // 6) fused bin + SpMM block 2 + linear: h1b -> out
  bucket_spmm2_linear_kernel<<<NB2c, 256, 0, stream>>>(
      h1b, S2, nA2, coarse2, WT, b, out);
}

// Round 10
// 182.690 us; speedup vs baseline: 1.6358x; 1.2117x over previous
//
#include <hip/hip_runtime.h>

#define DD 128

constexpr int cN0 = 100000, cN1 = 50000, cN2 = 10000;
constexpr int NB1c = (cN1 + 31) / 32;   // 1563 buckets of 32 dsts (graph 1)
constexpr int NB2c = (cN2 + 15) / 16;   // 625 buckets of 16 dsts (graph 2)
constexpr int CAP1 = 2048;              // mean 1024, sigma 32 -> safe
constexpr int CAP2 = 1024;              // mean 512,  sigma 23 -> safe

typedef unsigned long long ull;

// ---------------------------------------------------------------------------
// bf16 helpers (packed 2x bf16 in u32; lo 16 = even col, hi 16 = odd col)
// ---------------------------------------------------------------------------
__device__ __forceinline__ float bf_lo(unsigned int u) {
  return __uint_as_float(u << 16);
}
__device__ __forceinline__ float bf_hi(unsigned int u) {
  return __uint_as_float(u & 0xFFFF0000u);
}
__device__ __forceinline__ unsigned int pack_bf2(float a, float b) {
  unsigned int ua = __float_as_uint(a), ub = __float_as_uint(b);
  ua += 0x7FFFu + ((ua >> 16) & 1u);   // round-to-nearest-even
  ub += 0x7FFFu + ((ub >> 16) & 1u);
  return (ua >> 16) | (ub & 0xFFFF0000u);
}

// payload: hi32 = weight bits, lo32 = (src << 5) | dlow
#define PAY_GATHER(PK, VX, VY)                                       \
  {                                                                  \
    int s_ = ((int)(unsigned int)(PK)) >> 5;                         \
    unsigned int v_ = h_in[(size_t)s_ * 64 + lane];                  \
    float w_ = __uint_as_float((unsigned int)((PK) >> 32));          \
    VX += bf_lo(v_) * w_;                                            \
    VY += bf_hi(v_) * w_;                                            \
  }

// ---------------------------------------------------------------------------
// fp32 -> packed bf16, 8 floats / thread.
// ---------------------------------------------------------------------------
__global__ __launch_bounds__(256) void cvt_bf16_kernel(
    const float* __restrict__ in, unsigned int* __restrict__ outp, long long n8) {
  long long i = (long long)blockIdx.x * 256 + threadIdx.x;
  if (i >= n8) return;
  const float4* f4 = reinterpret_cast<const float4*>(in) + i * 2;
  float4 a = f4[0];
  float4 b = f4[1];
  uint4 o;
  o.x = pack_bf2(a.x, a.y);
  o.y = pack_bf2(a.z, a.w);
  o.z = pack_bf2(b.x, b.y);
  o.w = pack_bf2(b.z, b.w);
  reinterpret_cast<uint4*>(outp)[i] = o;
}

// ---------------------------------------------------------------------------
// Transpose W (128x128): WT[d][c] = W[c][d].
// ---------------------------------------------------------------------------
__global__ __launch_bounds__(256) void wt_kernel(
    const float* __restrict__ W, float* __restrict__ WT) {
  int idx = blockIdx.x * 256 + threadIdx.x;
  int c = idx >> 7;
  int d = idx & 127;
  WT[d * DD + c] = W[idx];
}

// ---------------------------------------------------------------------------
// Pass A (both graphs fused): per-block (4096 edges) LDS histogram over
// coarse buckets (d>>sh) -> bucket-major (bucket, block) count matrix.
// ---------------------------------------------------------------------------
__global__ __launch_bounds__(256) void passA_kernel(
    const int* __restrict__ d1, int E1, int nA1, int* __restrict__ bh1, int nblk1,
    const int* __restrict__ d2, int E2, int* __restrict__ bh2, int nblk2) {
  __shared__ int hist[NB1c];
  int lb = blockIdx.x;
  const int* dst; int E, NB, nblk, sh; int* bh;
  if (lb < nA1) { dst = d1; E = E1; NB = NB1c; nblk = nblk1; bh = bh1; sh = 5; }
  else { lb -= nA1; dst = d2; E = E2; NB = NB2c; nblk = nblk2; bh = bh2; sh = 4; }

  int t = threadIdx.x;
  for (int i = t; i < NB; i += 256) hist[i] = 0;
  __syncthreads();

  int eb = lb * 4096;
#pragma unroll
  for (int r = 0; r < 16; ++r) {
    int e = eb + r * 256 + t;
    if (e < E) atomicAdd(&hist[dst[e] >> sh], 1);
  }
  __syncthreads();
  for (int i = t; i < NB; i += 256) bh[(size_t)i * nblk + lb] = hist[i];
}

// ---------------------------------------------------------------------------
// Scan stage 1: per-4096-chunk exclusive scan (256 thr x 16 via int4).
// S stays CHUNK-LOCAL; consumers add bsum[idx>>12].
// ---------------------------------------------------------------------------
__global__ __launch_bounds__(256) void scan_blk2_kernel(
    const int* __restrict__ cnt1, int n1, int* __restrict__ ofs1, int* __restrict__ bsum1, int nb1,
    const int* __restrict__ cnt2, int n2, int* __restrict__ ofs2, int* __restrict__ bsum2) {
  const int* cnt; int n; int* ofs; int* bsum; int lb;
  if ((int)blockIdx.x < nb1) { cnt = cnt1; n = n1; ofs = ofs1; bsum = bsum1; lb = blockIdx.x; }
  else                       { cnt = cnt2; n = n2; ofs = ofs2; bsum = bsum2; lb = blockIdx.x - nb1; }

  __shared__ int tsum[256];
  int t = threadIdx.x;
  int base = lb * 4096 + t * 16;
  bool in = (base + 16 <= n);

  int v[16];
  if (in) {
    const int4* p4 = reinterpret_cast<const int4*>(cnt + base);
    int4 a = p4[0], b = p4[1], c = p4[2], d = p4[3];
    v[0]=a.x; v[1]=a.y; v[2]=a.z; v[3]=a.w;
    v[4]=b.x; v[5]=b.y; v[6]=b.z; v[7]=b.w;
    v[8]=c.x; v[9]=c.y; v[10]=c.z; v[11]=c.w;
    v[12]=d.x; v[13]=d.y; v[14]=d.z; v[15]=d.w;
  } else {
#pragma unroll
    for (int k = 0; k < 16; ++k) v[k] = 0;
  }
#pragma unroll
  for (int k = 1; k < 16; ++k) v[k] += v[k - 1];

  tsum[t] = v[15];
  __syncthreads();
  for (int d_ = 1; d_ < 256; d_ <<= 1) {
    int x = (t >= d_) ? tsum[t - d_] : 0;
    __syncthreads();
    tsum[t] += x;
    __syncthreads();
  }
  int ex = (t == 0) ? 0 : tsum[t - 1];

  if (in) {
    int4* q = reinterpret_cast<int4*>(ofs + base);
    q[0] = make_int4(ex,         ex + v[0],  ex + v[1],  ex + v[2]);
    q[1] = make_int4(ex + v[3],  ex + v[4],  ex + v[5],  ex + v[6]);
    q[2] = make_int4(ex + v[7],  ex + v[8],  ex + v[9],  ex + v[10]);
    q[3] = make_int4(ex + v[11], ex + v[12], ex + v[13], ex + v[14]);
  }
  if (t == 255) bsum[lb] = tsum[255];
}

// ---------------------------------------------------------------------------
// Scan stage 2: 1024-wide LDS scan of chunk sums -> exclusive (in place).
// ---------------------------------------------------------------------------
__global__ __launch_bounds__(1024) void scan_bsum2_kernel(
    int* __restrict__ bsum1, int nb1, int* __restrict__ bsum2, int nb2) {
  int* bsum; int nb;
  if (blockIdx.x == 0) { bsum = bsum1; nb = nb1; }
  else                 { bsum = bsum2; nb = nb2; }

  __shared__ int part[1024];
  int t = threadIdx.x;
  int orig = (t < nb) ? bsum[t] : 0;
  part[t] = orig;
  __syncthreads();
  for (int d_ = 1; d_ < 1024; d_ <<= 1) {
    int x = (t >= d_) ? part[t - d_] : 0;
    __syncthreads();
    part[t] += x;
    __syncthreads();
  }
  if (t < nb) bsum[t] = part[t] - orig;   // exclusive
}

// ---------------------------------------------------------------------------
// Pass B (both graphs fused): scatter full 8B payload (w | src<<5 | dlow)
// into coarse-bucket order. Ranks via per-block LDS atomics.
// pos = S[idx] + bsum[idx>>12] + rank.
// ---------------------------------------------------------------------------
__global__ __launch_bounds__(256) void passB_kernel(
    const int* __restrict__ d1, const int* __restrict__ s1, const float* __restrict__ w1,
    int E1, int nA1, const int* __restrict__ S1, const int* __restrict__ bs1,
    int nblk1, ull* __restrict__ coarse1,
    const int* __restrict__ d2, const int* __restrict__ s2, const float* __restrict__ w2,
    int E2, const int* __restrict__ S2, const int* __restrict__ bs2,
    int nblk2, ull* __restrict__ coarse2) {
  __shared__ int cnt[NB1c];
  int lb = blockIdx.x;
  const int* dst; const int* src; const float* ew;
  int E, NB, nblk, sh, msk; const int* S; const int* bs; ull* coarse;
  if (lb < nA1) {
    dst = d1; src = s1; ew = w1; E = E1; NB = NB1c; nblk = nblk1;
    S = S1; bs = bs1; coarse = coarse1; sh = 5; msk = 31;
  } else {
    lb -= nA1;
    dst = d2; src = s2; ew = w2; E = E2; NB = NB2c; nblk = nblk2;
    S = S2; bs = bs2; coarse = coarse2; sh = 4; msk = 15;
  }

  int t = threadIdx.x;
  for (int i = t; i < NB; i += 256) cnt[i] = 0;
  __syncthreads();

  int eb = lb * 4096;
#pragma unroll
  for (int r = 0; r < 16; ++r) {
    int e = eb + r * 256 + t;
    if (e < E) {
      int d_ = dst[e];
      int bkt = d_ >> sh;
      int rk = atomicAdd(&cnt[bkt], 1);
      size_t idx = (size_t)bkt * nblk + lb;
      int pos = S[idx] + bs[idx >> 12] + rk;
      ull pk = ((ull)__float_as_uint(ew[e]) << 32) |
               (unsigned int)((src[e] << 5) | (d_ & msk));
      __builtin_nontemporal_store(pk, coarse + pos);
    }
  }
}

// ---------------------------------------------------------------------------
// Fused fine-bin + SpMM block 1: one block per coarse bucket (32 dst rows).
// CAP1=2048 (16.8 KB LDS -> 8 blocks/CU). Unroll-8 gather.
// ---------------------------------------------------------------------------
__global__ __launch_bounds__(256) void bucket_spmm1_kernel(
    const unsigned int* __restrict__ h_in,   // xb
    const int* __restrict__ S, const int* __restrict__ bs, int nblk,
    const ull* __restrict__ coarse, int E,
    unsigned int* __restrict__ h1b) {
  __shared__ ull pay[CAP1];
  __shared__ int h32[32], c32[32], binofs[32];
  int b = blockIdx.x;
  int t = threadIdx.x;
  int wid = t >> 6, lane = t & 63;

  size_t i0 = (size_t)b * nblk;
  int base = S[i0] + bs[i0 >> 12];
  int end;
  if (b == NB1c - 1) end = E;
  else {
    size_t i1 = (size_t)(b + 1) * nblk;
    end = S[i1] + bs[i1 >> 12];
  }
  int count = end - base;

  if (count <= CAP1) {
    if (t < 32) { h32[t] = 0; c32[t] = 0; }
    __syncthreads();
    for (int i = base + t; i < end; i += 256)
      atomicAdd(&h32[(int)(unsigned int)coarse[i] & 31], 1);
    __syncthreads();
    if (t == 0) {
      int run = 0;
#pragma unroll
      for (int k = 0; k < 32; ++k) { binofs[k] = run; run += h32[k]; }
    }
    __syncthreads();
    for (int i = base + t; i < end; i += 256) {
      ull pk = coarse[i];
      int dl = (int)(unsigned int)pk & 31;
      int rk = atomicAdd(&c32[dl], 1);
      pay[binofs[dl] + rk] = pk;
    }
    __syncthreads();

#pragma unroll
    for (int r = 0; r < 8; ++r) {
      int dl = wid * 8 + r;
      int row = b * 32 + dl;
      if (row >= cN1) break;
      int lo = binofs[dl], hi = lo + h32[dl];
      float accx = 0.f, accy = 0.f, ax1 = 0.f, ay1 = 0.f;
      int j = lo;
      for (; j + 8 <= hi; j += 8) {
        ull p0 = pay[j],     p1 = pay[j + 1], p2 = pay[j + 2], p3 = pay[j + 3];
        ull p4 = pay[j + 4], p5 = pay[j + 5], p6 = pay[j + 6], p7 = pay[j + 7];
        PAY_GATHER(p0, accx, accy) PAY_GATHER(p1, ax1, ay1)
        PAY_GATHER(p2, accx, accy) PAY_GATHER(p3, ax1, ay1)
        PAY_GATHER(p4, accx, accy) PAY_GATHER(p5, ax1, ay1)
        PAY_GATHER(p6, accx, accy) PAY_GATHER(p7, ax1, ay1)
      }
      for (; j < hi; ++j) { ull p0 = pay[j]; PAY_GATHER(p0, accx, accy) }
      h1b[(size_t)row * 64 + lane] = pack_bf2(accx + ax1, accy + ay1);
    }
  } else {
    // slow fallback (statistically unreachable; kept for correctness)
    for (int r = 0; r < 8; ++r) {
      int dl = wid * 8 + r;
      int row = b * 32 + dl;
      if (row >= cN1) break;
      float accx = 0.f, accy = 0.f;
      for (int i = base; i < end; ++i) {
        ull pk = coarse[i];
        if (((int)(unsigned int)pk & 31) == dl) { PAY_GATHER(pk, accx, accy) }
      }
      h1b[(size_t)row * 64 + lane] = pack_bf2(accx, accy);
    }
  }
}

// ---------------------------------------------------------------------------
// Fused fine-bin + SpMM block 2 + linear: one block per coarse bucket of
// graph 2 (16 dst rows, 625 blocks). Each wave gathers 4 rows, then computes
// their linear outputs, streaming WT once per wave.
// ---------------------------------------------------------------------------
__global__ __launch_bounds__(256) void bucket_spmm2_linear_kernel(
    const unsigned int* __restrict__ h_in,   // h1b
    const int* __restrict__ S, const int* __restrict__ bs, int nblk,
    const ull* __restrict__ coarse, int E,
    const float* __restrict__ WT,
    const float* __restrict__ bias,
    float* __restrict__ out) {
  __shared__ ull pay[CAP2];
  __shared__ float hrow[16][DD];
  __shared__ int h16[16], c16[16], binofs[16];
  int b = blockIdx.x;
  int t = threadIdx.x;
  int wid = t >> 6, lane = t & 63;

  size_t i0 = (size_t)b * nblk;
  int base = S[i0] + bs[i0 >> 12];
  int end;
  if (b == NB2c - 1) end = E;
  else {
    size_t i1 = (size_t)(b + 1) * nblk;
    end = S[i1] + bs[i1 >> 12];
  }
  int count = end - base;

  if (count <= CAP2) {
    if (t < 16) { h16[t] = 0; c16[t] = 0; }
    __syncthreads();
    for (int i = base + t; i < end; i += 256)
      atomicAdd(&h16[(int)(unsigned int)coarse[i] & 15], 1);
    __syncthreads();
    if (t == 0) {
      int run = 0;
#pragma unroll
      for (int k = 0; k < 16; ++k) { binofs[k] = run; run += h16[k]; }
    }
    __syncthreads();
    for (int i = base + t; i < end; i += 256) {
      ull pk = coarse[i];
      int dl = (int)(unsigned int)pk & 15;
      int rk = atomicAdd(&c16[dl], 1);
      pay[binofs[dl] + rk] = pk;
    }
    __syncthreads();

#pragma unroll
    for (int r = 0; r < 4; ++r) {
      int dl = wid * 4 + r;
      int lo = binofs[dl], hi = lo + h16[dl];
      float accx = 0.f, accy = 0.f, ax1 = 0.f, ay1 = 0.f;
      int j = lo;
      for (; j + 8 <= hi; j += 8) {
        ull p0 = pay[j],     p1 = pay[j + 1], p2 = pay[j + 2], p3 = pay[j + 3];
        ull p4 = pay[j + 4], p5 = pay[j + 5], p6 = pay[j + 6], p7 = pay[j + 7];
        PAY_GATHER(p0, accx, accy) PAY_GATHER(p1, ax1, ay1)
        PAY_GATHER(p2, accx, accy) PAY_GATHER(p3, ax1, ay1)
        PAY_GATHER(p4, accx, accy) PAY_GATHER(p5, ax1, ay1)
        PAY_GATHER(p6, accx, accy) PAY_GATHER(p7, ax1, ay1)
      }
      for (; j < hi; ++j) { ull p0 = pay[j]; PAY_GATHER(p0, accx, accy) }
      float2 hv; hv.x = accx + ax1; hv.y = accy + ay1;
      *reinterpret_cast<float2*>(&hrow[dl][2 * lane]) = hv;
    }
  } else {
    for (int r = 0; r < 4; ++r) {
      int dl = wid * 4 + r;
      float accx = 0.f, accy = 0.f;
      for (int i = base; i < end; ++i) {
        ull pk = coarse[i];
        if (((int)(unsigned int)pk & 15) == dl) { PAY_GATHER(pk, accx, accy) }
      }
      float2 hv; hv.x = accx; hv.y = accy;
      *reinterpret_cast<float2*>(&hrow[dl][2 * lane]) = hv;
    }
  }
  // wave-synchronous: each wave reads only the hrow rows it wrote.

  float2 bb = reinterpret_cast<const float2*>(bias)[lane];
  float a0[4], a1[4];
#pragma unroll
  for (int r = 0; r < 4; ++r) { a0[r] = bb.x; a1[r] = bb.y; }

  const float* hbase = &hrow[wid * 4][0];
#pragma unroll 4
  for (int d = 0; d < DD; ++d) {
    float2 wv = *reinterpret_cast<const float2*>(WT + (size_t)d * DD + 2 * lane);
#pragma unroll
    for (int r = 0; r < 4; ++r) {
      float h = hbase[r * DD + d];   // LDS broadcast
      a0[r] += h * wv.x;
      a1[r] += h * wv.y;
    }
  }
#pragma unroll
  for (int r = 0; r < 4; ++r) {
    int row = b * 16 + wid * 4 + r;
    if (row < cN2) {
      float2 o; o.x = a0[r]; o.y = a1[r];
      reinterpret_cast<float2*>(out + (size_t)row * DD)[lane] = o;
    }
  }
}

static inline size_t align256(size_t x) { return (x + 255) & ~size_t(255); }
static inline int pad16i(int x) { return (x + 15) & ~15; }

extern "C" void kernel_launch(void* const* d_in, const int* in_sizes, int n_in,
                              void* d_out, int out_size, void* d_ws, size_t ws_size,
                              hipStream_t stream) {
  const float* x   = (const float*)d_in[0];
  const float* ew1 = (const float*)d_in[1];
  const float* ew2 = (const float*)d_in[2];
  const float* W   = (const float*)d_in[3];
  const float* b   = (const float*)d_in[4];
  const int* e1_src = (const int*)d_in[5];
  const int* e1_dst = (const int*)d_in[6];
  const int* e2_src = (const int*)d_in[7];
  const int* e2_dst = (const int*)d_in[8];
  float* out = (float*)d_out;

  int E1 = in_sizes[1];
  int E2 = in_sizes[2];

  int nA1 = (E1 + 4095) / 4096;           // 391
  int nA2 = (E2 + 4095) / 4096;           // 79
  int nc1 = pad16i(NB1c * nA1);           // 611136
  int nc2 = pad16i(NB2c * nA2);           // 49376
  int nbs1 = (nc1 + 4095) / 4096;         // 150
  int nbs2 = (nc2 + 4095) / 4096;         // 13

  // ---- workspace layout (~59 MB) ----
  char* p = (char*)d_ws;
  unsigned int* xb  = (unsigned int*)p;  p += align256((size_t)cN0 * DD * 2);
  unsigned int* h1b = (unsigned int*)p;  p += align256((size_t)cN1 * DD * 2);
  float* WT = (float*)p;                 p += align256((size_t)DD * DD * 4);
  int* bh1 = (int*)p;                    p += align256((size_t)(nc1 + 16) * 4);
  int* bh2 = (int*)p;                    p += align256((size_t)(nc2 + 16) * 4);
  int* S1  = (int*)p;                    p += align256((size_t)(nc1 + 16) * 4);
  int* S2  = (int*)p;                    p += align256((size_t)(nc2 + 16) * 4);
  int* bsum1 = (int*)p;                  p += align256(4096);
  int* bsum2 = (int*)p;                  p += align256(4096);
  ull* coarse1 = (ull*)p;                p += align256((size_t)E1 * 8);
  ull* coarse2 = (ull*)p;                p += align256((size_t)E2 * 8);

  // 1) x -> bf16; W -> W^T  (no memsets anywhere)
  {
    long long n8 = (long long)cN0 * DD / 8;
    cvt_bf16_kernel<<<(int)((n8 + 255) / 256), 256, 0, stream>>>(x, xb, n8);
  }
  wt_kernel<<<64, 256, 0, stream>>>(W, WT);

  // 2) pass A: coarse (bucket, block) histogram matrix
  passA_kernel<<<nA1 + nA2, 256, 0, stream>>>(
      e1_dst, E1, nA1, bh1, nA1, e2_dst, E2, bh2, nA2);

  // 3) scan -> chunk-local S + exclusive bsum (no add-back pass)
  scan_blk2_kernel<<<nbs1 + nbs2, 256, 0, stream>>>(
      bh1, nc1, S1, bsum1, nbs1, bh2, nc2, S2, bsum2);
  scan_bsum2_kernel<<<2, 1024, 0, stream>>>(bsum1, nbs1, bsum2, nbs2);

  // 4) pass B: scatter full payloads into coarse-bucket order
  passB_kernel<<<nA1 + nA2, 256, 0, stream>>>(
      e1_dst, e1_src, ew1, E1, nA1, S1, bsum1, nA1, coarse1,
      e2_dst, e2_src, ew2, E2, S2, bsum2, nA2, coarse2);

  // 5) fused bin + SpMM block 1: xb -> h1b
  bucket_spmm1_kernel<<<NB1c, 256, 0, stream>>>(
      xb, S1, bsum1, nA1, coarse1, E1, h1b);

  // 6) fused bin + SpMM block 2 + linear: h1b -> out
  bucket_spmm2_linear_kernel<<<NB2c, 256, 0, stream>>>(
      h1b, S2, bsum2, nA2, coarse2, E2, WT, b, out);
}

// Round 11
// 179.459 us; speedup vs baseline: 1.6652x; 1.0180x over previous
//
#include <hip/hip_runtime.h>

#define DD 128

constexpr int cN0 = 100000, cN1 = 50000, cN2 = 10000;
constexpr int NB1c = (cN1 + 31) / 32;   // 1563 buckets of 32 dsts (graph 1)
constexpr int NB2c = (cN2 + 15) / 16;   // 625 buckets of 16 dsts (graph 2)
constexpr int CAP1 = 2048;              // mean 1024, sigma 32 -> safe
constexpr int CAP2 = 1024;              // mean 512,  sigma 23 -> safe

typedef unsigned long long ull;

// ---------------------------------------------------------------------------
// bf16 helpers (packed 2x bf16 in u32; lo 16 = even col, hi 16 = odd col)
// ---------------------------------------------------------------------------
__device__ __forceinline__ float bf_lo(unsigned int u) {
  return __uint_as_float(u << 16);
}
__device__ __forceinline__ float bf_hi(unsigned int u) {
  return __uint_as_float(u & 0xFFFF0000u);
}
__device__ __forceinline__ unsigned int pack_bf2(float a, float b) {
  unsigned int ua = __float_as_uint(a), ub = __float_as_uint(b);
  ua += 0x7FFFu + ((ua >> 16) & 1u);   // round-to-nearest-even
  ub += 0x7FFFu + ((ub >> 16) & 1u);
  return (ua >> 16) | (ub & 0xFFFF0000u);
}

// payload: hi32 = weight bits, lo32 = (src << 5) | dlow
#define PAY_GATHER(PK, VX, VY)                                       \
  {                                                                  \
    int s_ = ((int)(unsigned int)(PK)) >> 5;                         \
    unsigned int v_ = h_in[(size_t)s_ * 64 + lane];                  \
    float w_ = __uint_as_float((unsigned int)((PK) >> 32));          \
    VX += bf_lo(v_) * w_;                                            \
    VY += bf_hi(v_) * w_;                                            \
  }

// ---------------------------------------------------------------------------
// fp32 -> packed bf16, 8 floats / thread.
// ---------------------------------------------------------------------------
__global__ __launch_bounds__(256) void cvt_bf16_kernel(
    const float* __restrict__ in, unsigned int* __restrict__ outp, long long n8) {
  long long i = (long long)blockIdx.x * 256 + threadIdx.x;
  if (i >= n8) return;
  const float4* f4 = reinterpret_cast<const float4*>(in) + i * 2;
  float4 a = f4[0];
  float4 b = f4[1];
  uint4 o;
  o.x = pack_bf2(a.x, a.y);
  o.y = pack_bf2(a.z, a.w);
  o.z = pack_bf2(b.x, b.y);
  o.w = pack_bf2(b.z, b.w);
  reinterpret_cast<uint4*>(outp)[i] = o;
}

// ---------------------------------------------------------------------------
// Transpose W (128x128): WT[d][c] = W[c][d].
// ---------------------------------------------------------------------------
__global__ __launch_bounds__(256) void wt_kernel(
    const float* __restrict__ W, float* __restrict__ WT) {
  int idx = blockIdx.x * 256 + threadIdx.x;
  int c = idx >> 7;
  int d = idx & 127;
  WT[d * DD + c] = W[idx];
}

// ---------------------------------------------------------------------------
// Pass A (both graphs fused): per-block (4096 edges, 1024 threads) LDS
// histogram over coarse buckets (d>>sh) -> (bucket, block) count matrix.
// ---------------------------------------------------------------------------
__global__ __launch_bounds__(1024) void passA_kernel(
    const int* __restrict__ d1, int E1, int nA1, int* __restrict__ bh1, int nblk1,
    const int* __restrict__ d2, int E2, int* __restrict__ bh2, int nblk2) {
  __shared__ int hist[NB1c];
  int lb = blockIdx.x;
  const int* dst; int E, NB, nblk, sh; int* bh;
  if (lb < nA1) { dst = d1; E = E1; NB = NB1c; nblk = nblk1; bh = bh1; sh = 5; }
  else { lb -= nA1; dst = d2; E = E2; NB = NB2c; nblk = nblk2; bh = bh2; sh = 4; }

  int t = threadIdx.x;
  for (int i = t; i < NB; i += 1024) hist[i] = 0;
  __syncthreads();

  int eb = lb * 4096;
#pragma unroll
  for (int r = 0; r < 4; ++r) {
    int e = eb + r * 1024 + t;
    if (e < E) atomicAdd(&hist[dst[e] >> sh], 1);
  }
  __syncthreads();
  for (int i = t; i < NB; i += 1024) bh[(size_t)i * nblk + lb] = hist[i];
}

// ---------------------------------------------------------------------------
// Scan stage 1: per-4096-chunk exclusive scan (256 thr x 16 via int4).
// S stays CHUNK-LOCAL; consumers add bsum[idx>>12].
// ---------------------------------------------------------------------------
__global__ __launch_bounds__(256) void scan_blk2_kernel(
    const int* __restrict__ cnt1, int n1, int* __restrict__ ofs1, int* __restrict__ bsum1, int nb1,
    const int* __restrict__ cnt2, int n2, int* __restrict__ ofs2, int* __restrict__ bsum2) {
  const int* cnt; int n; int* ofs; int* bsum; int lb;
  if ((int)blockIdx.x < nb1) { cnt = cnt1; n = n1; ofs = ofs1; bsum = bsum1; lb = blockIdx.x; }
  else                       { cnt = cnt2; n = n2; ofs = ofs2; bsum = bsum2; lb = blockIdx.x - nb1; }

  __shared__ int tsum[256];
  int t = threadIdx.x;
  int base = lb * 4096 + t * 16;
  bool in = (base + 16 <= n);

  int v[16];
  if (in) {
    const int4* p4 = reinterpret_cast<const int4*>(cnt + base);
    int4 a = p4[0], b = p4[1], c = p4[2], d = p4[3];
    v[0]=a.x; v[1]=a.y; v[2]=a.z; v[3]=a.w;
    v[4]=b.x; v[5]=b.y; v[6]=b.z; v[7]=b.w;
    v[8]=c.x; v[9]=c.y; v[10]=c.z; v[11]=c.w;
    v[12]=d.x; v[13]=d.y; v[14]=d.z; v[15]=d.w;
  } else {
#pragma unroll
    for (int k = 0; k < 16; ++k) v[k] = 0;
  }
#pragma unroll
  for (int k = 1; k < 16; ++k) v[k] += v[k - 1];

  tsum[t] = v[15];
  __syncthreads();
  for (int d_ = 1; d_ < 256; d_ <<= 1) {
    int x = (t >= d_) ? tsum[t - d_] : 0;
    __syncthreads();
    tsum[t] += x;
    __syncthreads();
  }
  int ex = (t == 0) ? 0 : tsum[t - 1];

  if (in) {
    int4* q = reinterpret_cast<int4*>(ofs + base);
    q[0] = make_int4(ex,         ex + v[0],  ex + v[1],  ex + v[2]);
    q[1] = make_int4(ex + v[3],  ex + v[4],  ex + v[5],  ex + v[6]);
    q[2] = make_int4(ex + v[7],  ex + v[8],  ex + v[9],  ex + v[10]);
    q[3] = make_int4(ex + v[11], ex + v[12], ex + v[13], ex + v[14]);
  }
  if (t == 255) bsum[lb] = tsum[255];
}

// ---------------------------------------------------------------------------
// Scan stage 2: 1024-wide LDS scan of chunk sums -> exclusive (in place).
// ---------------------------------------------------------------------------
__global__ __launch_bounds__(1024) void scan_bsum2_kernel(
    int* __restrict__ bsum1, int nb1, int* __restrict__ bsum2, int nb2) {
  int* bsum; int nb;
  if (blockIdx.x == 0) { bsum = bsum1; nb = nb1; }
  else                 { bsum = bsum2; nb = nb2; }

  __shared__ int part[1024];
  int t = threadIdx.x;
  int orig = (t < nb) ? bsum[t] : 0;
  part[t] = orig;
  __syncthreads();
  for (int d_ = 1; d_ < 1024; d_ <<= 1) {
    int x = (t >= d_) ? part[t - d_] : 0;
    __syncthreads();
    part[t] += x;
    __syncthreads();
  }
  if (t < nb) bsum[t] = part[t] - orig;   // exclusive
}

// ---------------------------------------------------------------------------
// Pass B (both graphs fused): scatter full 8B payload (w | src<<5 | dlow)
// into coarse-bucket order. 4096 edges / block, 1024 threads (4 edges each)
// for memory-level parallelism. Ranks via per-block LDS atomics.
// pos = S[idx] + bsum[idx>>12] + rank.
// ---------------------------------------------------------------------------
__global__ __launch_bounds__(1024) void passB_kernel(
    const int* __restrict__ d1, const int* __restrict__ s1, const float* __restrict__ w1,
    int E1, int nA1, const int* __restrict__ S1, const int* __restrict__ bs1,
    int nblk1, ull* __restrict__ coarse1,
    const int* __restrict__ d2, const int* __restrict__ s2, const float* __restrict__ w2,
    int E2, const int* __restrict__ S2, const int* __restrict__ bs2,
    int nblk2, ull* __restrict__ coarse2) {
  __shared__ int cnt[NB1c];
  int lb = blockIdx.x;
  const int* dst; const int* src; const float* ew;
  int E, NB, nblk, sh, msk; const int* S; const int* bs; ull* coarse;
  if (lb < nA1) {
    dst = d1; src = s1; ew = w1; E = E1; NB = NB1c; nblk = nblk1;
    S = S1; bs = bs1; coarse = coarse1; sh = 5; msk = 31;
  } else {
    lb -= nA1;
    dst = d2; src = s2; ew = w2; E = E2; NB = NB2c; nblk = nblk2;
    S = S2; bs = bs2; coarse = coarse2; sh = 4; msk = 15;
  }

  int t = threadIdx.x;
  for (int i = t; i < NB; i += 1024) cnt[i] = 0;
  __syncthreads();

  int eb = lb * 4096;
#pragma unroll
  for (int r = 0; r < 4; ++r) {
    int e = eb + r * 1024 + t;
    if (e < E) {
      int d_ = dst[e];
      int bkt = d_ >> sh;
      int rk = atomicAdd(&cnt[bkt], 1);
      size_t idx = (size_t)bkt * nblk + lb;
      int pos = S[idx] + bs[idx >> 12] + rk;
      ull pk = ((ull)__float_as_uint(ew[e]) << 32) |
               (unsigned int)((src[e] << 5) | (d_ & msk));
      __builtin_nontemporal_store(pk, coarse + pos);
    }
  }
}

// ---------------------------------------------------------------------------
// Fused fine-bin + SpMM block 1: one block per coarse bucket (32 dst rows).
// CAP1=2048 (16.8 KB LDS -> 8 blocks/CU). Unroll-8 gather.
// ---------------------------------------------------------------------------
__global__ __launch_bounds__(256) void bucket_spmm1_kernel(
    const unsigned int* __restrict__ h_in,   // xb
    const int* __restrict__ S, const int* __restrict__ bs, int nblk,
    const ull* __restrict__ coarse, int E,
    unsigned int* __restrict__ h1b) {
  __shared__ ull pay[CAP1];
  __shared__ int h32[32], c32[32], binofs[32];
  int b = blockIdx.x;
  int t = threadIdx.x;
  int wid = t >> 6, lane = t & 63;

  size_t i0 = (size_t)b * nblk;
  int base = S[i0] + bs[i0 >> 12];
  int end;
  if (b == NB1c - 1) end = E;
  else {
    size_t i1 = (size_t)(b + 1) * nblk;
    end = S[i1] + bs[i1 >> 12];
  }
  int count = end - base;

  if (count <= CAP1) {
    if (t < 32) { h32[t] = 0; c32[t] = 0; }
    __syncthreads();
    for (int i = base + t; i < end; i += 256)
      atomicAdd(&h32[(int)(unsigned int)coarse[i] & 31], 1);
    __syncthreads();
    if (t == 0) {
      int run = 0;
#pragma unroll
      for (int k = 0; k < 32; ++k) { binofs[k] = run; run += h32[k]; }
    }
    __syncthreads();
    for (int i = base + t; i < end; i += 256) {
      ull pk = coarse[i];
      int dl = (int)(unsigned int)pk & 31;
      int rk = atomicAdd(&c32[dl], 1);
      pay[binofs[dl] + rk] = pk;
    }
    __syncthreads();

#pragma unroll
    for (int r = 0; r < 8; ++r) {
      int dl = wid * 8 + r;
      int row = b * 32 + dl;
      if (row >= cN1) break;
      int lo = binofs[dl], hi = lo + h32[dl];
      float accx = 0.f, accy = 0.f, ax1 = 0.f, ay1 = 0.f;
      int j = lo;
      for (; j + 8 <= hi; j += 8) {
        ull p0 = pay[j],     p1 = pay[j + 1], p2 = pay[j + 2], p3 = pay[j + 3];
        ull p4 = pay[j + 4], p5 = pay[j + 5], p6 = pay[j + 6], p7 = pay[j + 7];
        PAY_GATHER(p0, accx, accy) PAY_GATHER(p1, ax1, ay1)
        PAY_GATHER(p2, accx, accy) PAY_GATHER(p3, ax1, ay1)
        PAY_GATHER(p4, accx, accy) PAY_GATHER(p5, ax1, ay1)
        PAY_GATHER(p6, accx, accy) PAY_GATHER(p7, ax1, ay1)
      }
      for (; j < hi; ++j) { ull p0 = pay[j]; PAY_GATHER(p0, accx, accy) }
      h1b[(size_t)row * 64 + lane] = pack_bf2(accx + ax1, accy + ay1);
    }
  } else {
    // slow fallback (statistically unreachable; kept for correctness)
    for (int r = 0; r < 8; ++r) {
      int dl = wid * 8 + r;
      int row = b * 32 + dl;
      if (row >= cN1) break;
      float accx = 0.f, accy = 0.f;
      for (int i = base; i < end; ++i) {
        ull pk = coarse[i];
        if (((int)(unsigned int)pk & 31) == dl) { PAY_GATHER(pk, accx, accy) }
      }
      h1b[(size_t)row * 64 + lane] = pack_bf2(accx, accy);
    }
  }
}

// ---------------------------------------------------------------------------
// Fused fine-bin + SpMM block 2 + linear: one block per coarse bucket of
// graph 2 (16 dst rows, 625 blocks). Each wave gathers 4 rows, then computes
// their linear outputs, streaming WT once per wave.
// ---------------------------------------------------------------------------
__global__ __launch_bounds__(256) void bucket_spmm2_linear_kernel(
    const unsigned int* __restrict__ h_in,   // h1b
    const int* __restrict__ S, const int* __restrict__ bs, int nblk,
    const ull* __restrict__ coarse, int E,
    const float* __restrict__ WT,
    const float* __restrict__ bias,
    float* __restrict__ out) {
  __shared__ ull pay[CAP2];
  __shared__ float hrow[16][DD];
  __shared__ int h16[16], c16[16], binofs[16];
  int b = blockIdx.x;
  int t = threadIdx.x;
  int wid = t >> 6, lane = t & 63;

  size_t i0 = (size_t)b * nblk;
  int base = S[i0] + bs[i0 >> 12];
  int end;
  if (b == NB2c - 1) end = E;
  else {
    size_t i1 = (size_t)(b + 1) * nblk;
    end = S[i1] + bs[i1 >> 12];
  }
  int count = end - base;

  if (count <= CAP2) {
    if (t < 16) { h16[t] = 0; c16[t] = 0; }
    __syncthreads();
    for (int i = base + t; i < end; i += 256)
      atomicAdd(&h16[(int)(unsigned int)coarse[i] & 15], 1);
    __syncthreads();
    if (t == 0) {
      int run = 0;
#pragma unroll
      for (int k = 0; k < 16; ++k) { binofs[k] = run; run += h16[k]; }
    }
    __syncthreads();
    for (int i = base + t; i < end; i += 256) {
      ull pk = coarse[i];
      int dl = (int)(unsigned int)pk & 15;
      int rk = atomicAdd(&c16[dl], 1);
      pay[binofs[dl] + rk] = pk;
    }
    __syncthreads();

#pragma unroll
    for (int r = 0; r < 4; ++r) {
      int dl = wid * 4 + r;
      int lo = binofs[dl], hi = lo + h16[dl];
      float accx = 0.f, accy = 0.f, ax1 = 0.f, ay1 = 0.f;
      int j = lo;
      for (; j + 8 <= hi; j += 8) {
        ull p0 = pay[j],     p1 = pay[j + 1], p2 = pay[j + 2], p3 = pay[j + 3];
        ull p4 = pay[j + 4], p5 = pay[j + 5], p6 = pay[j + 6], p7 = pay[j + 7];
        PAY_GATHER(p0, accx, accy) PAY_GATHER(p1, ax1, ay1)
        PAY_GATHER(p2, accx, accy) PAY_GATHER(p3, ax1, ay1)
        PAY_GATHER(p4, accx, accy) PAY_GATHER(p5, ax1, ay1)
        PAY_GATHER(p6, accx, accy) PAY_GATHER(p7, ax1, ay1)
      }
      for (; j < hi; ++j) { ull p0 = pay[j]; PAY_GATHER(p0, accx, accy) }
      float2 hv; hv.x = accx + ax1; hv.y = accy + ay1;
      *reinterpret_cast<float2*>(&hrow[dl][2 * lane]) = hv;
    }
  } else {
    for (int r = 0; r < 4; ++r) {
      int dl = wid * 4 + r;
      float accx = 0.f, accy = 0.f;
      for (int i = base; i < end; ++i) {
        ull pk = coarse[i];
        if (((int)(unsigned int)pk & 15) == dl) { PAY_GATHER(pk, accx, accy) }
      }
      float2 hv; hv.x = accx; hv.y = accy;
      *reinterpret_cast<float2*>(&hrow[dl][2 * lane]) = hv;
    }
  }
  // wave-synchronous: each wave reads only the hrow rows it wrote.

  float2 bb = reinterpret_cast<const float2*>(bias)[lane];
  float a0[4], a1[4];
#pragma unroll
  for (int r = 0; r < 4; ++r) { a0[r] = bb.x; a1[r] = bb.y; }

  const float* hbase = &hrow[wid * 4][0];
#pragma unroll 4
  for (int d = 0; d < DD; ++d) {
    float2 wv = *reinterpret_cast<const float2*>(WT + (size_t)d * DD + 2 * lane);
#pragma unroll
    for (int r = 0; r < 4; ++r) {
      float h = hbase[r * DD + d];   // LDS broadcast
      a0[r] += h * wv.x;
      a1[r] += h * wv.y;
    }
  }
#pragma unroll
  for (int r = 0; r < 4; ++r) {
    int row = b * 16 + wid * 4 + r;
    if (row < cN2) {
      float2 o; o.x = a0[r]; o.y = a1[r];
      reinterpret_cast<float2*>(out + (size_t)row * DD)[lane] = o;
    }
  }
}

static inline size_t align256(size_t x) { return (x + 255) & ~size_t(255); }
static inline int pad16i(int x) { return (x + 15) & ~15; }

extern "C" void kernel_launch(void* const* d_in, const int* in_sizes, int n_in,
                              void* d_out, int out_size, void* d_ws, size_t ws_size,
                              hipStream_t stream) {
  const float* x   = (const float*)d_in[0];
  const float* ew1 = (const float*)d_in[1];
  const float* ew2 = (const float*)d_in[2];
  const float* W   = (const float*)d_in[3];
  const float* b   = (const float*)d_in[4];
  const int* e1_src = (const int*)d_in[5];
  const int* e1_dst = (const int*)d_in[6];
  const int* e2_src = (const int*)d_in[7];
  const int* e2_dst = (const int*)d_in[8];
  float* out = (float*)d_out;

  int E1 = in_sizes[1];
  int E2 = in_sizes[2];

  int nA1 = (E1 + 4095) / 4096;           // 391
  int nA2 = (E2 + 4095) / 4096;           // 79
  int nc1 = pad16i(NB1c * nA1);           // 611136
  int nc2 = pad16i(NB2c * nA2);           // 49376
  int nbs1 = (nc1 + 4095) / 4096;         // 150
  int nbs2 = (nc2 + 4095) / 4096;         // 13

  // ---- workspace layout (~59 MB) ----
  char* p = (char*)d_ws;
  unsigned int* xb  = (unsigned int*)p;  p += align256((size_t)cN0 * DD * 2);
  unsigned int* h1b = (unsigned int*)p;  p += align256((size_t)cN1 * DD * 2);
  float* WT = (float*)p;                 p += align256((size_t)DD * DD * 4);
  int* bh1 = (int*)p;                    p += align256((size_t)(nc1 + 16) * 4);
  int* bh2 = (int*)p;                    p += align256((size_t)(nc2 + 16) * 4);
  int* S1  = (int*)p;                    p += align256((size_t)(nc1 + 16) * 4);
  int* S2  = (int*)p;                    p += align256((size_t)(nc2 + 16) * 4);
  int* bsum1 = (int*)p;                  p += align256(4096);
  int* bsum2 = (int*)p;                  p += align256(4096);
  ull* coarse1 = (ull*)p;                p += align256((size_t)E1 * 8);
  ull* coarse2 = (ull*)p;                p += align256((size_t)E2 * 8);

  // 1) x -> bf16; W -> W^T  (no memsets anywhere)
  {
    long long n8 = (long long)cN0 * DD / 8;
    cvt_bf16_kernel<<<(int)((n8 + 255) / 256), 256, 0, stream>>>(x, xb, n8);
  }
  wt_kernel<<<64, 256, 0, stream>>>(W, WT);

  // 2) pass A: coarse (bucket, block) histogram matrix (1024 thr / block)
  passA_kernel<<<nA1 + nA2, 1024, 0, stream>>>(
      e1_dst, E1, nA1, bh1, nA1, e2_dst, E2, bh2, nA2);

  // 3) scan -> chunk-local S + exclusive bsum (no add-back pass)
  scan_blk2_kernel<<<nbs1 + nbs2, 256, 0, stream>>>(
      bh1, nc1, S1, bsum1, nbs1, bh2, nc2, S2, bsum2);
  scan_bsum2_kernel<<<2, 1024, 0, stream>>>(bsum1, nbs1, bsum2, nbs2);

  // 4) pass B: scatter full payloads into coarse-bucket order (1024 thr)
  passB_kernel<<<nA1 + nA2, 1024, 0, stream>>>(
      e1_dst, e1_src, ew1, E1, nA1, S1, bsum1, nA1, coarse1,
      e2_dst, e2_src, ew2, E2, S2, bsum2, nA2, coarse2);

  // 5) fused bin + SpMM block 1: xb -> h1b
  bucket_spmm1_kernel<<<NB1c, 256, 0, stream>>>(
      xb, S1, bsum1, nA1, coarse1, E1, h1b);

  // 6) fused bin + SpMM block 2 + linear: h1b -> out
  bucket_spmm2_linear_kernel<<<NB2c, 256, 0, stream>>>(
      h1b, S2, bsum2, nA2, coarse2, E2, WT, b, out);
}

// Round 12
// 151.278 us; speedup vs baseline: 1.9755x; 1.1863x over previous
//
#include <hip/hip_runtime.h>

#define DD 128

constexpr int cN0 = 100000, cN1 = 50000, cN2 = 10000;
constexpr int NB1c = (cN1 + 31) / 32;   // 1563 buckets of 32 dsts (graph 1)
constexpr int NB2c = (cN2 + 15) / 16;   // 625 buckets of 16 dsts (graph 2)
constexpr int CAP1 = 2048;              // mean 1024, sigma 32 -> safe
constexpr int CAP2 = 1024;              // mean 512,  sigma 23 -> safe

typedef unsigned long long ull;

// ---------------------------------------------------------------------------
// bf16 helpers (packed 2x bf16 in u32; lo 16 = even col, hi 16 = odd col)
// ---------------------------------------------------------------------------
__device__ __forceinline__ float bf_lo(unsigned int u) {
  return __uint_as_float(u << 16);
}
__device__ __forceinline__ float bf_hi(unsigned int u) {
  return __uint_as_float(u & 0xFFFF0000u);
}
__device__ __forceinline__ unsigned int pack_bf2(float a, float b) {
  unsigned int ua = __float_as_uint(a), ub = __float_as_uint(b);
  ua += 0x7FFFu + ((ua >> 16) & 1u);   // round-to-nearest-even
  ub += 0x7FFFu + ((ub >> 16) & 1u);
  return (ua >> 16) | (ub & 0xFFFF0000u);
}

// payload: hi32 = weight bits, lo32 = (src << 5) | dlow
#define PAY_GATHER(PK, VX, VY)                                       \
  {                                                                  \
    int s_ = ((int)(unsigned int)(PK)) >> 5;                         \
    unsigned int v_ = h_in[(size_t)s_ * 64 + lane];                  \
    float w_ = __uint_as_float((unsigned int)((PK) >> 32));          \
    VX += bf_lo(v_) * w_;                                            \
    VY += bf_hi(v_) * w_;                                            \
  }

// ---------------------------------------------------------------------------
// fp32 -> packed bf16, 8 floats / thread.
// ---------------------------------------------------------------------------
__global__ __launch_bounds__(256) void cvt_bf16_kernel(
    const float* __restrict__ in, unsigned int* __restrict__ outp, long long n8) {
  long long i = (long long)blockIdx.x * 256 + threadIdx.x;
  if (i >= n8) return;
  const float4* f4 = reinterpret_cast<const float4*>(in) + i * 2;
  float4 a = f4[0];
  float4 b = f4[1];
  uint4 o;
  o.x = pack_bf2(a.x, a.y);
  o.y = pack_bf2(a.z, a.w);
  o.z = pack_bf2(b.x, b.y);
  o.w = pack_bf2(b.z, b.w);
  reinterpret_cast<uint4*>(outp)[i] = o;
}

// ---------------------------------------------------------------------------
// Transpose W (128x128): WT[d][c] = W[c][d].
// ---------------------------------------------------------------------------
__global__ __launch_bounds__(256) void wt_kernel(
    const float* __restrict__ W, float* __restrict__ WT) {
  int idx = blockIdx.x * 256 + threadIdx.x;
  int c = idx >> 7;
  int d = idx & 127;
  WT[d * DD + c] = W[idx];
}

// ---------------------------------------------------------------------------
// Pass A (both graphs fused): per-block (4096 edges, 1024 threads) LDS
// histogram over coarse buckets (d>>sh) -> (bucket, block) count matrix.
// ---------------------------------------------------------------------------
__global__ __launch_bounds__(1024) void passA_kernel(
    const int* __restrict__ d1, int E1, int nA1, int* __restrict__ bh1, int nblk1,
    const int* __restrict__ d2, int E2, int* __restrict__ bh2, int nblk2) {
  __shared__ int hist[NB1c];
  int lb = blockIdx.x;
  const int* dst; int E, NB, nblk, sh; int* bh;
  if (lb < nA1) { dst = d1; E = E1; NB = NB1c; nblk = nblk1; bh = bh1; sh = 5; }
  else { lb -= nA1; dst = d2; E = E2; NB = NB2c; nblk = nblk2; bh = bh2; sh = 4; }

  int t = threadIdx.x;
  for (int i = t; i < NB; i += 1024) hist[i] = 0;
  __syncthreads();

  int eb = lb * 4096;
#pragma unroll
  for (int r = 0; r < 4; ++r) {
    int e = eb + r * 1024 + t;
    if (e < E) atomicAdd(&hist[dst[e] >> sh], 1);
  }
  __syncthreads();
  for (int i = t; i < NB; i += 1024) bh[(size_t)i * nblk + lb] = hist[i];
}

// ---------------------------------------------------------------------------
// Scan stage 1: per-4096-chunk exclusive scan (256 thr x 16 via int4).
// S stays CHUNK-LOCAL; consumers add bsum[idx>>12].
// ---------------------------------------------------------------------------
__global__ __launch_bounds__(256) void scan_blk2_kernel(
    const int* __restrict__ cnt1, int n1, int* __restrict__ ofs1, int* __restrict__ bsum1, int nb1,
    const int* __restrict__ cnt2, int n2, int* __restrict__ ofs2, int* __restrict__ bsum2) {
  const int* cnt; int n; int* ofs; int* bsum; int lb;
  if ((int)blockIdx.x < nb1) { cnt = cnt1; n = n1; ofs = ofs1; bsum = bsum1; lb = blockIdx.x; }
  else                       { cnt = cnt2; n = n2; ofs = ofs2; bsum = bsum2; lb = blockIdx.x - nb1; }

  __shared__ int tsum[256];
  int t = threadIdx.x;
  int base = lb * 4096 + t * 16;
  bool in = (base + 16 <= n);

  int v[16];
  if (in) {
    const int4* p4 = reinterpret_cast<const int4*>(cnt + base);
    int4 a = p4[0], b = p4[1], c = p4[2], d = p4[3];
    v[0]=a.x; v[1]=a.y; v[2]=a.z; v[3]=a.w;
    v[4]=b.x; v[5]=b.y; v[6]=b.z; v[7]=b.w;
    v[8]=c.x; v[9]=c.y; v[10]=c.z; v[11]=c.w;
    v[12]=d.x; v[13]=d.y; v[14]=d.z; v[15]=d.w;
  } else {
#pragma unroll
    for (int k = 0; k < 16; ++k) v[k] = 0;
  }
#pragma unroll
  for (int k = 1; k < 16; ++k) v[k] += v[k - 1];

  tsum[t] = v[15];
  __syncthreads();
  for (int d_ = 1; d_ < 256; d_ <<= 1) {
    int x = (t >= d_) ? tsum[t - d_] : 0;
    __syncthreads();
    tsum[t] += x;
    __syncthreads();
  }
  int ex = (t == 0) ? 0 : tsum[t - 1];

  if (in) {
    int4* q = reinterpret_cast<int4*>(ofs + base);
    q[0] = make_int4(ex,         ex + v[0],  ex + v[1],  ex + v[2]);
    q[1] = make_int4(ex + v[3],  ex + v[4],  ex + v[5],  ex + v[6]);
    q[2] = make_int4(ex + v[7],  ex + v[8],  ex + v[9],  ex + v[10]);
    q[3] = make_int4(ex + v[11], ex + v[12], ex + v[13], ex + v[14]);
  }
  if (t == 255) bsum[lb] = tsum[255];
}

// ---------------------------------------------------------------------------
// Scan stage 2: 1024-wide LDS scan of chunk sums -> exclusive (in place).
// ---------------------------------------------------------------------------
__global__ __launch_bounds__(1024) void scan_bsum2_kernel(
    int* __restrict__ bsum1, int nb1, int* __restrict__ bsum2, int nb2) {
  int* bsum; int nb;
  if (blockIdx.x == 0) { bsum = bsum1; nb = nb1; }
  else                 { bsum = bsum2; nb = nb2; }

  __shared__ int part[1024];
  int t = threadIdx.x;
  int orig = (t < nb) ? bsum[t] : 0;
  part[t] = orig;
  __syncthreads();
  for (int d_ = 1; d_ < 1024; d_ <<= 1) {
    int x = (t >= d_) ? part[t - d_] : 0;
    __syncthreads();
    part[t] += x;
    __syncthreads();
  }
  if (t < nb) bsum[t] = part[t] - orig;   // exclusive
}

// ---------------------------------------------------------------------------
// Pass B v2 (both graphs fused): LDS-binned scatter. Per 4096-edge block:
// LDS hist -> in-block scan -> place payloads bucket-sorted in LDS -> write
// out in sorted order so consecutive lanes hit consecutive global addresses
// (wave-coalesced stores; R11 showed lane-random 8B scatter is the wall).
// ---------------------------------------------------------------------------
__global__ __launch_bounds__(1024) void passB_kernel(
    const int* __restrict__ d1, const int* __restrict__ s1, const float* __restrict__ w1,
    int E1, int nA1, const int* __restrict__ S1, const int* __restrict__ bs1,
    int nblk1, ull* __restrict__ coarse1,
    const int* __restrict__ d2, const int* __restrict__ s2, const float* __restrict__ w2,
    int E2, const int* __restrict__ S2, const int* __restrict__ bs2,
    int nblk2, ull* __restrict__ coarse2) {
  __shared__ int cnt[NB1c];        // hist, then reused as placement cursor
  __shared__ int lscan[NB1c];      // exclusive prefix within block
  __shared__ int cellst[NB1c];     // absolute global cell start
  __shared__ int part[1024];
  __shared__ ull pay[4096];
  __shared__ unsigned short bkt_of[4096];

  int lb = blockIdx.x;
  const int* dst; const int* src; const float* ew;
  int E, NB, nblk, sh, msk; const int* S; const int* bs; ull* coarse;
  if (lb < nA1) {
    dst = d1; src = s1; ew = w1; E = E1; NB = NB1c; nblk = nblk1;
    S = S1; bs = bs1; coarse = coarse1; sh = 5; msk = 31;
  } else {
    lb -= nA1;
    dst = d2; src = s2; ew = w2; E = E2; NB = NB2c; nblk = nblk2;
    S = S2; bs = bs2; coarse = coarse2; sh = 4; msk = 15;
  }

  int t = threadIdx.x;
  int eb = lb * 4096;
  int ecount = E - eb; if (ecount > 4096) ecount = 4096;

  for (int i = t; i < NB; i += 1024) cnt[i] = 0;
  __syncthreads();

  // load 4 edges into registers + histogram
  ull pk0 = 0, pk1 = 0, pk2 = 0, pk3 = 0;
  int bk0 = -1, bk1 = -1, bk2 = -1, bk3 = -1;
#define LOADE(R, PK, BK)                                              \
  {                                                                   \
    int e = eb + (R) * 1024 + t;                                      \
    if (e < E) {                                                      \
      int d_ = dst[e];                                                \
      BK = d_ >> sh;                                                  \
      PK = ((ull)__float_as_uint(ew[e]) << 32) |                      \
           (unsigned int)((src[e] << 5) | (d_ & msk));                \
      atomicAdd(&cnt[BK], 1);                                         \
    }                                                                 \
  }
  LOADE(0, pk0, bk0) LOADE(1, pk1, bk1) LOADE(2, pk2, bk2) LOADE(3, pk3, bk3)
#undef LOADE
  __syncthreads();

  // in-block scan of cnt -> lscan (each thread owns 2 consecutive buckets)
  int i0 = 2 * t, i1 = 2 * t + 1;
  int c0 = (i0 < NB) ? cnt[i0] : 0;
  int c1 = (i1 < NB) ? cnt[i1] : 0;
  part[t] = c0 + c1;
  __syncthreads();
  for (int d_ = 1; d_ < 1024; d_ <<= 1) {
    int x = (t >= d_) ? part[t - d_] : 0;
    __syncthreads();
    part[t] += x;
    __syncthreads();
  }
  int ex = (t == 0) ? 0 : part[t - 1];
  if (i0 < NB) lscan[i0] = ex;
  if (i1 < NB) lscan[i1] = ex + c0;
  __syncthreads();

  // cell starts (absolute) + re-init cnt as placement cursor
  for (int i = t; i < NB; i += 1024) {
    size_t idx = (size_t)i * nblk + lb;
    cellst[i] = S[idx] + bs[idx >> 12];
    cnt[i] = lscan[i];
  }
  __syncthreads();

  // place payloads bucket-sorted into LDS
#define PLACE(PK, BK)                                                 \
  if (BK >= 0) {                                                      \
    int pos = atomicAdd(&cnt[BK], 1);                                 \
    pay[pos] = PK;                                                    \
    bkt_of[pos] = (unsigned short)(BK);                               \
  }
  PLACE(pk0, bk0) PLACE(pk1, bk1) PLACE(pk2, bk2) PLACE(pk3, bk3)
#undef PLACE
  __syncthreads();

  // write out in sorted order: consecutive lanes -> consecutive addresses
#pragma unroll
  for (int r = 0; r < 4; ++r) {
    int p = r * 1024 + t;
    if (p < ecount) {
      int b_ = bkt_of[p];
      int addr = cellst[b_] + (p - lscan[b_]);
      __builtin_nontemporal_store(pay[p], coarse + addr);
    }
  }
}

// ---------------------------------------------------------------------------
// Fused fine-bin + SpMM block 1: one block per coarse bucket (32 dst rows).
// CAP1=2048 (16.8 KB LDS -> 8 blocks/CU). Unroll-8 gather.
// ---------------------------------------------------------------------------
__global__ __launch_bounds__(256) void bucket_spmm1_kernel(
    const unsigned int* __restrict__ h_in,   // xb
    const int* __restrict__ S, const int* __restrict__ bs, int nblk,
    const ull* __restrict__ coarse, int E,
    unsigned int* __restrict__ h1b) {
  __shared__ ull pay[CAP1];
  __shared__ int h32[32], c32[32], binofs[32];
  int b = blockIdx.x;
  int t = threadIdx.x;
  int wid = t >> 6, lane = t & 63;

  size_t i0 = (size_t)b * nblk;
  int base = S[i0] + bs[i0 >> 12];
  int end;
  if (b == NB1c - 1) end = E;
  else {
    size_t i1 = (size_t)(b + 1) * nblk;
    end = S[i1] + bs[i1 >> 12];
  }
  int count = end - base;

  if (count <= CAP1) {
    if (t < 32) { h32[t] = 0; c32[t] = 0; }
    __syncthreads();
    for (int i = base + t; i < end; i += 256)
      atomicAdd(&h32[(int)(unsigned int)coarse[i] & 31], 1);
    __syncthreads();
    if (t == 0) {
      int run = 0;
#pragma unroll
      for (int k = 0; k < 32; ++k) { binofs[k] = run; run += h32[k]; }
    }
    __syncthreads();
    for (int i = base + t; i < end; i += 256) {
      ull pk = coarse[i];
      int dl = (int)(unsigned int)pk & 31;
      int rk = atomicAdd(&c32[dl], 1);
      pay[binofs[dl] + rk] = pk;
    }
    __syncthreads();

#pragma unroll
    for (int r = 0; r < 8; ++r) {
      int dl = wid * 8 + r;
      int row = b * 32 + dl;
      if (row >= cN1) break;
      int lo = binofs[dl], hi = lo + h32[dl];
      float accx = 0.f, accy = 0.f, ax1 = 0.f, ay1 = 0.f;
      int j = lo;
      for (; j + 8 <= hi; j += 8) {
        ull p0 = pay[j],     p1 = pay[j + 1], p2 = pay[j + 2], p3 = pay[j + 3];
        ull p4 = pay[j + 4], p5 = pay[j + 5], p6 = pay[j + 6], p7 = pay[j + 7];
        PAY_GATHER(p0, accx, accy) PAY_GATHER(p1, ax1, ay1)
        PAY_GATHER(p2, accx, accy) PAY_GATHER(p3, ax1, ay1)
        PAY_GATHER(p4, accx, accy) PAY_GATHER(p5, ax1, ay1)
        PAY_GATHER(p6, accx, accy) PAY_GATHER(p7, ax1, ay1)
      }
      for (; j < hi; ++j) { ull p0 = pay[j]; PAY_GATHER(p0, accx, accy) }
      h1b[(size_t)row * 64 + lane] = pack_bf2(accx + ax1, accy + ay1);
    }
  } else {
    // slow fallback (statistically unreachable; kept for correctness)
    for (int r = 0; r < 8; ++r) {
      int dl = wid * 8 + r;
      int row = b * 32 + dl;
      if (row >= cN1) break;
      float accx = 0.f, accy = 0.f;
      for (int i = base; i < end; ++i) {
        ull pk = coarse[i];
        if (((int)(unsigned int)pk & 31) == dl) { PAY_GATHER(pk, accx, accy) }
      }
      h1b[(size_t)row * 64 + lane] = pack_bf2(accx, accy);
    }
  }
}

// ---------------------------------------------------------------------------
// Fused fine-bin + SpMM block 2 + linear: one block per coarse bucket of
// graph 2 (16 dst rows, 625 blocks). Each wave gathers 4 rows, then computes
// their linear outputs, streaming WT once per wave.
// ---------------------------------------------------------------------------
__global__ __launch_bounds__(256) void bucket_spmm2_linear_kernel(
    const unsigned int* __restrict__ h_in,   // h1b
    const int* __restrict__ S, const int* __restrict__ bs, int nblk,
    const ull* __restrict__ coarse, int E,
    const float* __restrict__ WT,
    const float* __restrict__ bias,
    float* __restrict__ out) {
  __shared__ ull pay[CAP2];
  __shared__ float hrow[16][DD];
  __shared__ int h16[16], c16[16], binofs[16];
  int b = blockIdx.x;
  int t = threadIdx.x;
  int wid = t >> 6, lane = t & 63;

  size_t i0 = (size_t)b * nblk;
  int base = S[i0] + bs[i0 >> 12];
  int end;
  if (b == NB2c - 1) end = E;
  else {
    size_t i1 = (size_t)(b + 1) * nblk;
    end = S[i1] + bs[i1 >> 12];
  }
  int count = end - base;

  if (count <= CAP2) {
    if (t < 16) { h16[t] = 0; c16[t] = 0; }
    __syncthreads();
    for (int i = base + t; i < end; i += 256)
      atomicAdd(&h16[(int)(unsigned int)coarse[i] & 15], 1);
    __syncthreads();
    if (t == 0) {
      int run = 0;
#pragma unroll
      for (int k = 0; k < 16; ++k) { binofs[k] = run; run += h16[k]; }
    }
    __syncthreads();
    for (int i = base + t; i < end; i += 256) {
      ull pk = coarse[i];
      int dl = (int)(unsigned int)pk & 15;
      int rk = atomicAdd(&c16[dl], 1);
      pay[binofs[dl] + rk] = pk;
    }
    __syncthreads();

#pragma unroll
    for (int r = 0; r < 4; ++r) {
      int dl = wid * 4 + r;
      int lo = binofs[dl], hi = lo + h16[dl];
      float accx = 0.f, accy = 0.f, ax1 = 0.f, ay1 = 0.f;
      int j = lo;
      for (; j + 8 <= hi; j += 8) {
        ull p0 = pay[j],     p1 = pay[j + 1], p2 = pay[j + 2], p3 = pay[j + 3];
        ull p4 = pay[j + 4], p5 = pay[j + 5], p6 = pay[j + 6], p7 = pay[j + 7];
        PAY_GATHER(p0, accx, accy) PAY_GATHER(p1, ax1, ay1)
        PAY_GATHER(p2, accx, accy) PAY_GATHER(p3, ax1, ay1)
        PAY_GATHER(p4, accx, accy) PAY_GATHER(p5, ax1, ay1)
        PAY_GATHER(p6, accx, accy) PAY_GATHER(p7, ax1, ay1)
      }
      for (; j < hi; ++j) { ull p0 = pay[j]; PAY_GATHER(p0, accx, accy) }
      float2 hv; hv.x = accx + ax1; hv.y = accy + ay1;
      *reinterpret_cast<float2*>(&hrow[dl][2 * lane]) = hv;
    }
  } else {
    for (int r = 0; r < 4; ++r) {
      int dl = wid * 4 + r;
      float accx = 0.f, accy = 0.f;
      for (int i = base; i < end; ++i) {
        ull pk = coarse[i];
        if (((int)(unsigned int)pk & 15) == dl) { PAY_GATHER(pk, accx, accy) }
      }
      float2 hv; hv.x = accx; hv.y = accy;
      *reinterpret_cast<float2*>(&hrow[dl][2 * lane]) = hv;
    }
  }
  // wave-synchronous: each wave reads only the hrow rows it wrote.

  float2 bb = reinterpret_cast<const float2*>(bias)[lane];
  float a0[4], a1[4];
#pragma unroll
  for (int r = 0; r < 4; ++r) { a0[r] = bb.x; a1[r] = bb.y; }

  const float* hbase = &hrow[wid * 4][0];
#pragma unroll 4
  for (int d = 0; d < DD; ++d) {
    float2 wv = *reinterpret_cast<const float2*>(WT + (size_t)d * DD + 2 * lane);
#pragma unroll
    for (int r = 0; r < 4; ++r) {
      float h = hbase[r * DD + d];   // LDS broadcast
      a0[r] += h * wv.x;
      a1[r] += h * wv.y;
    }
  }
#pragma unroll
  for (int r = 0; r < 4; ++r) {
    int row = b * 16 + wid * 4 + r;
    if (row < cN2) {
      float2 o; o.x = a0[r]; o.y = a1[r];
      reinterpret_cast<float2*>(out + (size_t)row * DD)[lane] = o;
    }
  }
}

static inline size_t align256(size_t x) { return (x + 255) & ~size_t(255); }
static inline int pad16i(int x) { return (x + 15) & ~15; }

extern "C" void kernel_launch(void* const* d_in, const int* in_sizes, int n_in,
                              void* d_out, int out_size, void* d_ws, size_t ws_size,
                              hipStream_t stream) {
  const float* x   = (const float*)d_in[0];
  const float* ew1 = (const float*)d_in[1];
  const float* ew2 = (const float*)d_in[2];
  const float* W   = (const float*)d_in[3];
  const float* b   = (const float*)d_in[4];
  const int* e1_src = (const int*)d_in[5];
  const int* e1_dst = (const int*)d_in[6];
  const int* e2_src = (const int*)d_in[7];
  const int* e2_dst = (const int*)d_in[8];
  float* out = (float*)d_out;

  int E1 = in_sizes[1];
  int E2 = in_sizes[2];

  int nA1 = (E1 + 4095) / 4096;           // 391
  int nA2 = (E2 + 4095) / 4096;           // 79
  int nc1 = pad16i(NB1c * nA1);           // 611136
  int nc2 = pad16i(NB2c * nA2);           // 49376
  int nbs1 = (nc1 + 4095) / 4096;         // 150
  int nbs2 = (nc2 + 4095) / 4096;         // 13

  // ---- workspace layout (~59 MB) ----
  char* p = (char*)d_ws;
  unsigned int* xb  = (unsigned int*)p;  p += align256((size_t)cN0 * DD * 2);
  unsigned int* h1b = (unsigned int*)p;  p += align256((size_t)cN1 * DD * 2);
  float* WT = (float*)p;                 p += align256((size_t)DD * DD * 4);
  int* bh1 = (int*)p;                    p += align256((size_t)(nc1 + 16) * 4);
  int* bh2 = (int*)p;                    p += align256((size_t)(nc2 + 16) * 4);
  int* S1  = (int*)p;                    p += align256((size_t)(nc1 + 16) * 4);
  int* S2  = (int*)p;                    p += align256((size_t)(nc2 + 16) * 4);
  int* bsum1 = (int*)p;                  p += align256(4096);
  int* bsum2 = (int*)p;                  p += align256(4096);
  ull* coarse1 = (ull*)p;                p += align256((size_t)E1 * 8);
  ull* coarse2 = (ull*)p;                p += align256((size_t)E2 * 8);

  // 1) x -> bf16; W -> W^T  (no memsets anywhere)
  {
    long long n8 = (long long)cN0 * DD / 8;
    cvt_bf16_kernel<<<(int)((n8 + 255) / 256), 256, 0, stream>>>(x, xb, n8);
  }
  wt_kernel<<<64, 256, 0, stream>>>(W, WT);

  // 2) pass A: coarse (bucket, block) histogram matrix (1024 thr / block)
  passA_kernel<<<nA1 + nA2, 1024, 0, stream>>>(
      e1_dst, E1, nA1, bh1, nA1, e2_dst, E2, bh2, nA2);

  // 3) scan -> chunk-local S + exclusive bsum (no add-back pass)
  scan_blk2_kernel<<<nbs1 + nbs2, 256, 0, stream>>>(
      bh1, nc1, S1, bsum1, nbs1, bh2, nc2, S2, bsum2);
  scan_bsum2_kernel<<<2, 1024, 0, stream>>>(bsum1, nbs1, bsum2, nbs2);

  // 4) pass B v2: LDS-binned, wave-coalesced scatter
  passB_kernel<<<nA1 + nA2, 1024, 0, stream>>>(
      e1_dst, e1_src, ew1, E1, nA1, S1, bsum1, nA1, coarse1,
      e2_dst, e2_src, ew2, E2, S2, bsum2, nA2, coarse2);

  // 5) fused bin + SpMM block 1: xb -> h1b
  bucket_spmm1_kernel<<<NB1c, 256, 0, stream>>>(
      xb, S1, bsum1, nA1, coarse1, E1, h1b);

  // 6) fused bin + SpMM block 2 + linear: h1b -> out
  bucket_spmm2_linear_kernel<<<NB2c, 256, 0, stream>>>(
      h1b, S2, bsum2, nA2, coarse2, E2, WT, b, out);
}

// Round 13
// 148.796 us; speedup vs baseline: 2.0084x; 1.0167x over previous
//
#include <hip/hip_runtime.h>

#define DD 128

constexpr int cN0 = 100000, cN1 = 50000, cN2 = 10000;
constexpr int NB1c = (cN1 + 31) / 32;   // 1563 buckets of 32 dsts (graph 1)
constexpr int NB2c = (cN2 + 15) / 16;   // 625 buckets of 16 dsts (graph 2)
constexpr int CAP1 = 2048;              // mean 1024, sigma 32 -> safe
constexpr int CAP2 = 1024;              // mean 512,  sigma 23 -> safe

typedef unsigned long long ull;

// ---------------------------------------------------------------------------
// bf16 helpers (packed 2x bf16 in u32; lo 16 = even col, hi 16 = odd col)
// ---------------------------------------------------------------------------
__device__ __forceinline__ float bf_lo(unsigned int u) {
  return __uint_as_float(u << 16);
}
__device__ __forceinline__ float bf_hi(unsigned int u) {
  return __uint_as_float(u & 0xFFFF0000u);
}
__device__ __forceinline__ unsigned int pack_bf2(float a, float b) {
  unsigned int ua = __float_as_uint(a), ub = __float_as_uint(b);
  ua += 0x7FFFu + ((ua >> 16) & 1u);   // round-to-nearest-even
  ub += 0x7FFFu + ((ub >> 16) & 1u);
  return (ua >> 16) | (ub & 0xFFFF0000u);
}

// payload: hi32 = weight bits, lo32 = (src << 5) | dlow
#define PAY_GATHER(PK, VX, VY)                                       \
  {                                                                  \
    int s_ = ((int)(unsigned int)(PK)) >> 5;                         \
    unsigned int v_ = h_in[(size_t)s_ * 64 + lane];                  \
    float w_ = __uint_as_float((unsigned int)((PK) >> 32));          \
    VX += bf_lo(v_) * w_;                                            \
    VY += bf_hi(v_) * w_;                                            \
  }

// ---------------------------------------------------------------------------
// One-wave exclusive scan of raw[0..nb) into lds_out (nb <= 192).
// Caller must __syncthreads() after.
// ---------------------------------------------------------------------------
__device__ __forceinline__ void wave_scan_bsum(
    const int* __restrict__ raw, int nb, int* lds_out, int tid) {
  if (tid < 64) {
    int carry = 0;
    for (int base = 0; base < nb; base += 64) {
      int i = base + tid;
      int orig = (i < nb) ? raw[i] : 0;
      int v = orig;
      for (int d = 1; d < 64; d <<= 1) {
        int u = __shfl_up(v, d);
        if (tid >= d) v += u;
      }
      if (i < nb) lds_out[i] = carry + v - orig;
      carry += __shfl(v, 63);
    }
  }
}

// ---------------------------------------------------------------------------
// Prep kernel (one launch): blocks [0, nA) run pass A (coarse histogram),
// blocks [nA, nA+ncvt) convert x -> bf16, last 16 blocks transpose W.
// Latency-bound hist overlaps BW-bound cvt on the machine.
// ---------------------------------------------------------------------------
__global__ __launch_bounds__(1024) void prep_kernel(
    const int* __restrict__ d1, int E1, int nA1, int* __restrict__ bh1,
    const int* __restrict__ d2, int E2, int nA2, int* __restrict__ bh2,
    const float* __restrict__ x, unsigned int* __restrict__ xb, long long n8,
    int ncvt, const float* __restrict__ W, float* __restrict__ WT) {
  __shared__ int hist[NB1c];
  int blk = blockIdx.x;
  int t = threadIdx.x;
  int nA = nA1 + nA2;

  if (blk < nA) {
    // ---- pass A ----
    const int* dst; int E, NB, nblk, sh; int* bh; int lb;
    if (blk < nA1) { dst = d1; E = E1; NB = NB1c; nblk = nA1; bh = bh1; sh = 5; lb = blk; }
    else { dst = d2; E = E2; NB = NB2c; nblk = nA2; bh = bh2; sh = 4; lb = blk - nA1; }

    for (int i = t; i < NB; i += 1024) hist[i] = 0;
    __syncthreads();

    int eb = lb * 4096;
#pragma unroll
    for (int r = 0; r < 4; ++r) {
      int e = eb + r * 1024 + t;
      if (e < E) atomicAdd(&hist[dst[e] >> sh], 1);
    }
    __syncthreads();
    for (int i = t; i < NB; i += 1024) bh[(size_t)i * nblk + lb] = hist[i];
  } else if (blk < nA + ncvt) {
    // ---- cvt x -> bf16 (8 floats / thread) ----
    long long i = (long long)(blk - nA) * 1024 + t;
    if (i < n8) {
      const float4* f4 = reinterpret_cast<const float4*>(x) + i * 2;
      float4 a = f4[0];
      float4 b = f4[1];
      uint4 o;
      o.x = pack_bf2(a.x, a.y);
      o.y = pack_bf2(a.z, a.w);
      o.z = pack_bf2(b.x, b.y);
      o.w = pack_bf2(b.z, b.w);
      reinterpret_cast<uint4*>(xb)[i] = o;
    }
  } else {
    // ---- transpose W ----
    int idx = (blk - nA - ncvt) * 1024 + t;
    if (idx < DD * DD) {
      int c = idx >> 7;
      int d = idx & 127;
      WT[d * DD + c] = W[idx];
    }
  }
}

// ---------------------------------------------------------------------------
// Scan stage 1: per-4096-chunk exclusive scan (256 thr x 16 via int4).
// S stays CHUNK-LOCAL; bsum holds RAW chunk totals (consumers scan them).
// ---------------------------------------------------------------------------
__global__ __launch_bounds__(256) void scan_blk2_kernel(
    const int* __restrict__ cnt1, int n1, int* __restrict__ ofs1, int* __restrict__ bsum1, int nb1,
    const int* __restrict__ cnt2, int n2, int* __restrict__ ofs2, int* __restrict__ bsum2) {
  const int* cnt; int n; int* ofs; int* bsum; int lb;
  if ((int)blockIdx.x < nb1) { cnt = cnt1; n = n1; ofs = ofs1; bsum = bsum1; lb = blockIdx.x; }
  else                       { cnt = cnt2; n = n2; ofs = ofs2; bsum = bsum2; lb = blockIdx.x - nb1; }

  __shared__ int tsum[256];
  int t = threadIdx.x;
  int base = lb * 4096 + t * 16;
  bool in = (base + 16 <= n);

  int v[16];
  if (in) {
    const int4* p4 = reinterpret_cast<const int4*>(cnt + base);
    int4 a = p4[0], b = p4[1], c = p4[2], d = p4[3];
    v[0]=a.x; v[1]=a.y; v[2]=a.z; v[3]=a.w;
    v[4]=b.x; v[5]=b.y; v[6]=b.z; v[7]=b.w;
    v[8]=c.x; v[9]=c.y; v[10]=c.z; v[11]=c.w;
    v[12]=d.x; v[13]=d.y; v[14]=d.z; v[15]=d.w;
  } else {
#pragma unroll
    for (int k = 0; k < 16; ++k) v[k] = 0;
  }
#pragma unroll
  for (int k = 1; k < 16; ++k) v[k] += v[k - 1];

  tsum[t] = v[15];
  __syncthreads();
  for (int d_ = 1; d_ < 256; d_ <<= 1) {
    int x = (t >= d_) ? tsum[t - d_] : 0;
    __syncthreads();
    tsum[t] += x;
    __syncthreads();
  }
  int ex = (t == 0) ? 0 : tsum[t - 1];

  if (in) {
    int4* q = reinterpret_cast<int4*>(ofs + base);
    q[0] = make_int4(ex,         ex + v[0],  ex + v[1],  ex + v[2]);
    q[1] = make_int4(ex + v[3],  ex + v[4],  ex + v[5],  ex + v[6]);
    q[2] = make_int4(ex + v[7],  ex + v[8],  ex + v[9],  ex + v[10]);
    q[3] = make_int4(ex + v[11], ex + v[12], ex + v[13], ex + v[14]);
  }
  if (t == 255) bsum[lb] = tsum[255];
}

// ---------------------------------------------------------------------------
// Pass B (LDS-binned, wave-coalesced scatter). Prologue scans raw bsum.
// ---------------------------------------------------------------------------
__global__ __launch_bounds__(1024) void passB_kernel(
    const int* __restrict__ d1, const int* __restrict__ s1, const float* __restrict__ w1,
    int E1, int nA1, const int* __restrict__ S1, const int* __restrict__ bs1, int nbs1,
    int nblk1, ull* __restrict__ coarse1,
    const int* __restrict__ d2, const int* __restrict__ s2, const float* __restrict__ w2,
    int E2, const int* __restrict__ S2, const int* __restrict__ bs2, int nbs2,
    int nblk2, ull* __restrict__ coarse2) {
  __shared__ int cnt[NB1c];        // hist, then reused as placement cursor
  __shared__ int lscan[NB1c];      // exclusive prefix within block
  __shared__ int cellst[NB1c];     // absolute global cell start
  __shared__ int part[1024];
  __shared__ int sbs[192];         // scanned chunk bases
  __shared__ ull pay[4096];
  __shared__ unsigned short bkt_of[4096];

  int lb = blockIdx.x;
  const int* dst; const int* src; const float* ew;
  int E, NB, nblk, sh, msk, nbs; const int* S; const int* bs; ull* coarse;
  if (lb < nA1) {
    dst = d1; src = s1; ew = w1; E = E1; NB = NB1c; nblk = nblk1;
    S = S1; bs = bs1; nbs = nbs1; coarse = coarse1; sh = 5; msk = 31;
  } else {
    lb -= nA1;
    dst = d2; src = s2; ew = w2; E = E2; NB = NB2c; nblk = nblk2;
    S = S2; bs = bs2; nbs = nbs2; coarse = coarse2; sh = 4; msk = 15;
  }

  int t = threadIdx.x;
  int eb = lb * 4096;
  int ecount = E - eb; if (ecount > 4096) ecount = 4096;

  wave_scan_bsum(bs, nbs, sbs, t);
  for (int i = t; i < NB; i += 1024) cnt[i] = 0;
  __syncthreads();

  // load 4 edges into registers + histogram
  ull pk0 = 0, pk1 = 0, pk2 = 0, pk3 = 0;
  int bk0 = -1, bk1 = -1, bk2 = -1, bk3 = -1;
#define LOADE(R, PK, BK)                                              \
  {                                                                   \
    int e = eb + (R) * 1024 + t;                                      \
    if (e < E) {                                                      \
      int d_ = dst[e];                                                \
      BK = d_ >> sh;                                                  \
      PK = ((ull)__float_as_uint(ew[e]) << 32) |                      \
           (unsigned int)((src[e] << 5) | (d_ & msk));                \
      atomicAdd(&cnt[BK], 1);                                         \
    }                                                                 \
  }
  LOADE(0, pk0, bk0) LOADE(1, pk1, bk1) LOADE(2, pk2, bk2) LOADE(3, pk3, bk3)
#undef LOADE
  __syncthreads();

  // in-block scan of cnt -> lscan (each thread owns 2 consecutive buckets)
  int i0 = 2 * t, i1 = 2 * t + 1;
  int c0 = (i0 < NB) ? cnt[i0] : 0;
  int c1 = (i1 < NB) ? cnt[i1] : 0;
  part[t] = c0 + c1;
  __syncthreads();
  for (int d_ = 1; d_ < 1024; d_ <<= 1) {
    int x = (t >= d_) ? part[t - d_] : 0;
    __syncthreads();
    part[t] += x;
    __syncthreads();
  }
  int ex = (t == 0) ? 0 : part[t - 1];
  if (i0 < NB) lscan[i0] = ex;
  if (i1 < NB) lscan[i1] = ex + c0;
  __syncthreads();

  // cell starts (absolute) + re-init cnt as placement cursor
  for (int i = t; i < NB; i += 1024) {
    size_t idx = (size_t)i * nblk + lb;
    cellst[i] = S[idx] + sbs[idx >> 12];
    cnt[i] = lscan[i];
  }
  __syncthreads();

  // place payloads bucket-sorted into LDS
#define PLACE(PK, BK)                                                 \
  if (BK >= 0) {                                                      \
    int pos = atomicAdd(&cnt[BK], 1);                                 \
    pay[pos] = PK;                                                    \
    bkt_of[pos] = (unsigned short)(BK);                               \
  }
  PLACE(pk0, bk0) PLACE(pk1, bk1) PLACE(pk2, bk2) PLACE(pk3, bk3)
#undef PLACE
  __syncthreads();

  // write out in sorted order: consecutive lanes -> consecutive addresses
#pragma unroll
  for (int r = 0; r < 4; ++r) {
    int p = r * 1024 + t;
    if (p < ecount) {
      int b_ = bkt_of[p];
      int addr = cellst[b_] + (p - lscan[b_]);
      __builtin_nontemporal_store(pay[p], coarse + addr);
    }
  }
}

// ---------------------------------------------------------------------------
// Fused fine-bin + SpMM block 1: one block per coarse bucket (32 dst rows).
// ---------------------------------------------------------------------------
__global__ __launch_bounds__(256) void bucket_spmm1_kernel(
    const unsigned int* __restrict__ h_in,   // xb
    const int* __restrict__ S, const int* __restrict__ bs, int nbs, int nblk,
    const ull* __restrict__ coarse, int E,
    unsigned int* __restrict__ h1b) {
  __shared__ ull pay[CAP1];
  __shared__ int h32[32], c32[32], binofs[32];
  __shared__ int sbs[192];
  int b = blockIdx.x;
  int t = threadIdx.x;
  int wid = t >> 6, lane = t & 63;

  wave_scan_bsum(bs, nbs, sbs, t);
  if (t < 32) { h32[t] = 0; c32[t] = 0; }
  __syncthreads();

  size_t i0 = (size_t)b * nblk;
  int base = S[i0] + sbs[i0 >> 12];
  int end;
  if (b == NB1c - 1) end = E;
  else {
    size_t i1 = (size_t)(b + 1) * nblk;
    end = S[i1] + sbs[i1 >> 12];
  }
  int count = end - base;

  if (count <= CAP1) {
    for (int i = base + t; i < end; i += 256)
      atomicAdd(&h32[(int)(unsigned int)coarse[i] & 31], 1);
    __syncthreads();
    if (t == 0) {
      int run = 0;
#pragma unroll
      for (int k = 0; k < 32; ++k) { binofs[k] = run; run += h32[k]; }
    }
    __syncthreads();
    for (int i = base + t; i < end; i += 256) {
      ull pk = coarse[i];
      int dl = (int)(unsigned int)pk & 31;
      int rk = atomicAdd(&c32[dl], 1);
      pay[binofs[dl] + rk] = pk;
    }
    __syncthreads();

#pragma unroll
    for (int r = 0; r < 8; ++r) {
      int dl = wid * 8 + r;
      int row = b * 32 + dl;
      if (row >= cN1) break;
      int lo = binofs[dl], hi = lo + h32[dl];
      float accx = 0.f, accy = 0.f, ax1 = 0.f, ay1 = 0.f;
      int j = lo;
      for (; j + 8 <= hi; j += 8) {
        ull p0 = pay[j],     p1 = pay[j + 1], p2 = pay[j + 2], p3 = pay[j + 3];
        ull p4 = pay[j + 4], p5 = pay[j + 5], p6 = pay[j + 6], p7 = pay[j + 7];
        PAY_GATHER(p0, accx, accy) PAY_GATHER(p1, ax1, ay1)
        PAY_GATHER(p2, accx, accy) PAY_GATHER(p3, ax1, ay1)
        PAY_GATHER(p4, accx, accy) PAY_GATHER(p5, ax1, ay1)
        PAY_GATHER(p6, accx, accy) PAY_GATHER(p7, ax1, ay1)
      }
      for (; j < hi; ++j) { ull p0 = pay[j]; PAY_GATHER(p0, accx, accy) }
      h1b[(size_t)row * 64 + lane] = pack_bf2(accx + ax1, accy + ay1);
    }
  } else {
    // slow fallback (statistically unreachable; kept for correctness)
    for (int r = 0; r < 8; ++r) {
      int dl = wid * 8 + r;
      int row = b * 32 + dl;
      if (row >= cN1) break;
      float accx = 0.f, accy = 0.f;
      for (int i = base; i < end; ++i) {
        ull pk = coarse[i];
        if (((int)(unsigned int)pk & 31) == dl) { PAY_GATHER(pk, accx, accy) }
      }
      h1b[(size_t)row * 64 + lane] = pack_bf2(accx, accy);
    }
  }
}

// ---------------------------------------------------------------------------
// Fused fine-bin + SpMM block 2 + linear: one block per coarse bucket of
// graph 2 (16 dst rows, 625 blocks).
// ---------------------------------------------------------------------------
__global__ __launch_bounds__(256) void bucket_spmm2_linear_kernel(
    const unsigned int* __restrict__ h_in,   // h1b
    const int* __restrict__ S, const int* __restrict__ bs, int nbs, int nblk,
    const ull* __restrict__ coarse, int E,
    const float* __restrict__ WT,
    const float* __restrict__ bias,
    float* __restrict__ out) {
  __shared__ ull pay[CAP2];
  __shared__ float hrow[16][DD];
  __shared__ int h16[16], c16[16], binofs[16];
  __shared__ int sbs[64];
  int b = blockIdx.x;
  int t = threadIdx.x;
  int wid = t >> 6, lane = t & 63;

  wave_scan_bsum(bs, nbs, sbs, t);
  if (t < 16) { h16[t] = 0; c16[t] = 0; }
  __syncthreads();

  size_t i0 = (size_t)b * nblk;
  int base = S[i0] + sbs[i0 >> 12];
  int end;
  if (b == NB2c - 1) end = E;
  else {
    size_t i1 = (size_t)(b + 1) * nblk;
    end = S[i1] + sbs[i1 >> 12];
  }
  int count = end - base;

  if (count <= CAP2) {
    for (int i = base + t; i < end; i += 256)
      atomicAdd(&h16[(int)(unsigned int)coarse[i] & 15], 1);
    __syncthreads();
    if (t == 0) {
      int run = 0;
#pragma unroll
      for (int k = 0; k < 16; ++k) { binofs[k] = run; run += h16[k]; }
    }
    __syncthreads();
    for (int i = base + t; i < end; i += 256) {
      ull pk = coarse[i];
      int dl = (int)(unsigned int)pk & 15;
      int rk = atomicAdd(&c16[dl], 1);
      pay[binofs[dl] + rk] = pk;
    }
    __syncthreads();

#pragma unroll
    for (int r = 0; r < 4; ++r) {
      int dl = wid * 4 + r;
      int lo = binofs[dl], hi = lo + h16[dl];
      float accx = 0.f, accy = 0.f, ax1 = 0.f, ay1 = 0.f;
      int j = lo;
      for (; j + 8 <= hi; j += 8) {
        ull p0 = pay[j],     p1 = pay[j + 1], p2 = pay[j + 2], p3 = pay[j + 3];
        ull p4 = pay[j + 4], p5 = pay[j + 5], p6 = pay[j + 6], p7 = pay[j + 7];
        PAY_GATHER(p0, accx, accy) PAY_GATHER(p1, ax1, ay1)
        PAY_GATHER(p2, accx, accy) PAY_GATHER(p3, ax1, ay1)
        PAY_GATHER(p4, accx, accy) PAY_GATHER(p5, ax1, ay1)
        PAY_GATHER(p6, accx, accy) PAY_GATHER(p7, ax1, ay1)
      }
      for (; j < hi; ++j) { ull p0 = pay[j]; PAY_GATHER(p0, accx, accy) }
      float2 hv; hv.x = accx + ax1; hv.y = accy + ay1;
      *reinterpret_cast<float2*>(&hrow[dl][2 * lane]) = hv;
    }
  } else {
    for (int r = 0; r < 4; ++r) {
      int dl = wid * 4 + r;
      float accx = 0.f, accy = 0.f;
      for (int i = base; i < end; ++i) {
        ull pk = coarse[i];
        if (((int)(unsigned int)pk & 15) == dl) { PAY_GATHER(pk, accx, accy) }
      }
      float2 hv; hv.x = accx; hv.y = accy;
      *reinterpret_cast<float2*>(&hrow[dl][2 * lane]) = hv;
    }
  }
  // wave-synchronous: each wave reads only the hrow rows it wrote.

  float2 bb = reinterpret_cast<const float2*>(bias)[lane];
  float a0[4], a1[4];
#pragma unroll
  for (int r = 0; r < 4; ++r) { a0[r] = bb.x; a1[r] = bb.y; }

  const float* hbase = &hrow[wid * 4][0];
#pragma unroll 4
  for (int d = 0; d < DD; ++d) {
    float2 wv = *reinterpret_cast<const float2*>(WT + (size_t)d * DD + 2 * lane);
#pragma unroll
    for (int r = 0; r < 4; ++r) {
      float h = hbase[r * DD + d];   // LDS broadcast
      a0[r] += h * wv.x;
      a1[r] += h * wv.y;
    }
  }
#pragma unroll
  for (int r = 0; r < 4; ++r) {
    int row = b * 16 + wid * 4 + r;
    if (row < cN2) {
      float2 o; o.x = a0[r]; o.y = a1[r];
      reinterpret_cast<float2*>(out + (size_t)row * DD)[lane] = o;
    }
  }
}

static inline size_t align256(size_t x) { return (x + 255) & ~size_t(255); }
static inline int pad16i(int x) { return (x + 15) & ~15; }

extern "C" void kernel_launch(void* const* d_in, const int* in_sizes, int n_in,
                              void* d_out, int out_size, void* d_ws, size_t ws_size,
                              hipStream_t stream) {
  const float* x   = (const float*)d_in[0];
  const float* ew1 = (const float*)d_in[1];
  const float* ew2 = (const float*)d_in[2];
  const float* W   = (const float*)d_in[3];
  const float* b   = (const float*)d_in[4];
  const int* e1_src = (const int*)d_in[5];
  const int* e1_dst = (const int*)d_in[6];
  const int* e2_src = (const int*)d_in[7];
  const int* e2_dst = (const int*)d_in[8];
  float* out = (float*)d_out;

  int E1 = in_sizes[1];
  int E2 = in_sizes[2];

  int nA1 = (E1 + 4095) / 4096;           // 391
  int nA2 = (E2 + 4095) / 4096;           // 79
  int nc1 = pad16i(NB1c * nA1);           // 611136
  int nc2 = pad16i(NB2c * nA2);           // 49376
  int nbs1 = (nc1 + 4095) / 4096;         // 150
  int nbs2 = (nc2 + 4095) / 4096;         // 13

  long long n8 = (long long)cN0 * DD / 8; // 1.6M uint4 outputs
  int ncvt = (int)((n8 + 1023) / 1024);   // 1563 cvt blocks
  int nwt  = (DD * DD + 1023) / 1024;     // 16 wt blocks

  // ---- workspace layout (~59 MB) ----
  char* p = (char*)d_ws;
  unsigned int* xb  = (unsigned int*)p;  p += align256((size_t)cN0 * DD * 2);
  unsigned int* h1b = (unsigned int*)p;  p += align256((size_t)cN1 * DD * 2);
  float* WT = (float*)p;                 p += align256((size_t)DD * DD * 4);
  int* bh1 = (int*)p;                    p += align256((size_t)(nc1 + 16) * 4);
  int* bh2 = (int*)p;                    p += align256((size_t)(nc2 + 16) * 4);
  int* S1  = (int*)p;                    p += align256((size_t)(nc1 + 16) * 4);
  int* S2  = (int*)p;                    p += align256((size_t)(nc2 + 16) * 4);
  int* bsum1 = (int*)p;                  p += align256(4096);
  int* bsum2 = (int*)p;                  p += align256(4096);
  ull* coarse1 = (ull*)p;                p += align256((size_t)E1 * 8);
  ull* coarse2 = (ull*)p;                p += align256((size_t)E2 * 8);

  // 1) prep: passA + x->bf16 + W^T in ONE launch (overlapping pipes)
  prep_kernel<<<nA1 + nA2 + ncvt + nwt, 1024, 0, stream>>>(
      e1_dst, E1, nA1, bh1, e2_dst, E2, nA2, bh2,
      x, xb, n8, ncvt, W, WT);

  // 2) scan -> chunk-local S + RAW chunk sums (consumers scan bsum)
  scan_blk2_kernel<<<nbs1 + nbs2, 256, 0, stream>>>(
      bh1, nc1, S1, bsum1, nbs1, bh2, nc2, S2, bsum2);

  // 3) pass B: LDS-binned, wave-coalesced scatter
  passB_kernel<<<nA1 + nA2, 1024, 0, stream>>>(
      e1_dst, e1_src, ew1, E1, nA1, S1, bsum1, nbs1, nA1, coarse1,
      e2_dst, e2_src, ew2, E2, S2, bsum2, nbs2, nA2, coarse2);

  // 4) fused bin + SpMM block 1: xb -> h1b
  bucket_spmm1_kernel<<<NB1c, 256, 0, stream>>>(
      xb, S1, bsum1, nbs1, nA1, coarse1, E1, h1b);

  // 5) fused bin + SpMM block 2 + linear: h1b -> out
  bucket_spmm2_linear_kernel<<<NB2c, 256, 0, stream>>>(
      h1b, S2, bsum2, nbs2, nA2, coarse2, E2, WT, b, out);
}